// Round 12
// baseline (412.555 us; speedup 1.0000x reference)
//
#include <hip/hip_runtime.h>
#include <math.h>

#define NN 50000
#define NNP (NN + 1)          // +1 dummy zero row per slice
#define NE 800000
#define NEP 1150000           // NE + 7*NN upper bound on padded edge count
#define NBLK 49               // ceil(NN/1024)
#define NBKT 7                // dst-range buckets (d >> 13)
#define BCAP 262144           // per-bucket bin capacity

// bf16 helpers (RNE pack, shift unpack)
__device__ inline unsigned int f2bf(float f) {
  unsigned int u = __float_as_uint(f);
  return (u + 0x7fffu + ((u >> 16) & 1u)) >> 16;
}
__device__ inline unsigned int pack2bf(float lo, float hi) {
  return f2bf(lo) | (f2bf(hi) << 16);
}
__device__ inline float bflo(unsigned int p) { return __uint_as_float(p << 16); }
__device__ inline float bfhi(unsigned int p) { return __uint_as_float(p & 0xffff0000u); }

// ---------------- init: zero deg8/gstat/binCnt, prefill csr with dummy ----------------

__global__ __launch_bounds__(256) void k_init(int* __restrict__ deg8, float* __restrict__ gstat,
                                              int* __restrict__ csr, int* __restrict__ binCnt) {
  int i = blockIdx.x * 256 + threadIdx.x;
  if (i < NEP) csr[i] = NN;
  if (i < 8 * NN) deg8[i] = 0;
  if (i < 512) gstat[i] = 0.f;   // [gsum0|gsq0|gsum1|gsq1] x128
  if (i < NBKT) binCnt[i] = 0;
}

// ---------------- pass A: degree count + dst-range binning ----------------

__global__ __launch_bounds__(1024) void k_binA(const int* __restrict__ src, const int* __restrict__ dst,
                                               int* __restrict__ deg8, int* __restrict__ binCnt,
                                               int2* __restrict__ bin) {
  __shared__ int lcnt[NBKT], lbase[NBKT];
  int tid = threadIdx.x;
  if (tid < NBKT) lcnt[tid] = 0;
  __syncthreads();
  int e = blockIdx.x * 1024 + tid;
  bool act = e < NE;
  int d = 0, s = 0, b = 0, rank = 0;
  if (act) {
    d = dst[e]; s = src[e];
    b = d >> 13;                       // 0..6
    atomicAdd(&deg8[(e & 7) * NN + d], 1);
    rank = atomicAdd(&lcnt[b], 1);
  }
  __syncthreads();
  if (tid < NBKT && lcnt[tid] > 0) lbase[tid] = atomicAdd(&binCnt[tid], lcnt[tid]);
  __syncthreads();
  if (act) bin[(size_t)b * BCAP + lbase[b] + rank] = make_int2(d, s);
}

// scan PADDED total degrees; also emit true total degree
__global__ __launch_bounds__(1024) void k_scan1(const int* __restrict__ deg8, int* __restrict__ degtot,
                                                int* __restrict__ excl, int* __restrict__ blksum) {
  __shared__ int sm[1024];
  int t = threadIdx.x;
  int i = blockIdx.x * 1024 + t;
  int tot = 0;
  if (i < NN) {
    #pragma unroll
    for (int j = 0; j < 8; j++) tot += deg8[j * NN + i];
    degtot[i] = tot;
  }
  int v = (i < NN) ? ((tot + 7) & ~7) : 0;
  sm[t] = v;
  __syncthreads();
  for (int off = 1; off < 1024; off <<= 1) {
    int x = (t >= off) ? sm[t - off] : 0;
    __syncthreads();
    sm[t] += x;
    __syncthreads();
  }
  if (i < NN) excl[i] = sm[t] - v;
  if (t == 1023) blksum[blockIdx.x] = sm[t];
}

__global__ void k_scan2(const int* __restrict__ blksum, int* __restrict__ blkoff,
                        int* __restrict__ rowstart) {
  int t = threadIdx.x;  // 64 threads, one wave
  int orig = (t < NBLK) ? blksum[t] : 0;
  int v = orig;
  #pragma unroll
  for (int off = 1; off < 64; off <<= 1) {
    int u = __shfl_up(v, off);
    if (t >= off) v += u;
  }
  if (t < NBLK) blkoff[t] = v - orig;
  if (t == NBLK - 1) rowstart[NN] = v;  // padded edge total
}

// finalize rowstart; dis; preload cursor; zero bf16 hs pad rows + h2 pad row
__global__ __launch_bounds__(256) void k_scan3(int* __restrict__ excl, const int* __restrict__ blkoff,
                                               const int* __restrict__ degtot, int* __restrict__ cursor,
                                               float* __restrict__ dis,
                                               unsigned short* __restrict__ hs16, float* __restrict__ h2) {
  int i = blockIdx.x * 256 + threadIdx.x;
  if (i < NN) {
    int rs = excl[i] + blkoff[i >> 10];
    excl[i] = rs;
    cursor[i] = rs;
    dis[i] = rsqrtf((float)degtot[i] + 1.0f);
  }
  if (i < 64) {   // hs16 pad row: 2 slices x 64 bf16 = 2 x 32 uints
    int slice = i >> 5, c = i & 31;
    ((unsigned int*)(hs16 + (size_t)slice * ((size_t)NNP * 64) + (size_t)NN * 64))[c] = 0u;
  }
  if (i < 32) h2[(size_t)NN * 32 + i] = 0.f;
}

// ---------------- pass B: scatter within XCD-pinned bucket ----------------

__global__ __launch_bounds__(256) void k_fillB(const int2* __restrict__ bin, const int* __restrict__ binCnt,
                                               int* __restrict__ cursor, int* __restrict__ csr_src) {
  int b = blockIdx.x & 7;
  if (b >= NBKT) return;
  int q = blockIdx.x >> 3;             // 0..63
  int cnt = binCnt[b];
  const int2* __restrict__ B = bin + (size_t)b * BCAP;
  for (int i = q * 256 + threadIdx.x; i < cnt; i += 64 * 256) {
    int2 ds = B[i];
    int p = atomicAdd(&cursor[ds.x], 1);
    csr_src[p] = ds.y;
  }
}

// ---------------- SGEMM 128->128: 128x128 tiles, 8x8 micro, conflict-free split-B ----------
// hs16[slice][node][64] bf16 (slice = col>>6, stride NNP rows), pre-scaled by dis[row].
// Bs[2][8][68]: Bs[0][k][g*4+j] = W[k][g*8+j], Bs[1][k][g*4+j] = W[k][g*8+4+j].
// b-fragment reads hit 16 addresses at 16 B stride (contiguous 256 B -> 2-way, free);
// a-fragment reads are 4-address broadcasts. 64 FMA per 4 ds_read_b128.

__global__ __launch_bounds__(256) void k_gemm128(const float* __restrict__ X, const float* __restrict__ W,
                                                 const float* __restrict__ dis,
                                                 unsigned short* __restrict__ hs16, int M) {
  __shared__ float As[8][128];
  __shared__ float Bs[2][8][68];
  const int tid = threadIdx.x;
  const int rg = tid >> 4;   // 0..15: 8-row group
  const int cg = tid & 15;   // 0..15: 8-col group
  const int row0 = blockIdx.x * 128;

  float acc[8][8];
  #pragma unroll
  for (int i = 0; i < 8; i++)
    #pragma unroll
    for (int j = 0; j < 8; j++) acc[i][j] = 0.f;

  const int lr = tid >> 1;        // 0..127
  const int lk = (tid & 1) * 4;   // 0 or 4
  const int wk = tid >> 5;        // 0..7
  const int wc = tid & 31;        // 0..31

  for (int kt = 0; kt < 128; kt += 8) {
    float4 av = make_float4(0.f, 0.f, 0.f, 0.f);
    int gr = row0 + lr;
    if (gr < M) av = *(const float4*)(X + (size_t)gr * 128 + kt + lk);
    As[lk + 0][lr] = av.x; As[lk + 1][lr] = av.y; As[lk + 2][lr] = av.z; As[lk + 3][lr] = av.w;
    float4 bv = *(const float4*)(W + (size_t)(kt + wk) * 128 + wc * 4);
    int half = wc & 1, bg = wc >> 1;
    Bs[half][wk][bg * 4 + 0] = bv.x;
    Bs[half][wk][bg * 4 + 1] = bv.y;
    Bs[half][wk][bg * 4 + 2] = bv.z;
    Bs[half][wk][bg * 4 + 3] = bv.w;
    __syncthreads();
    #pragma unroll
    for (int kk = 0; kk < 8; kk++) {
      float a[8], b[8];
      *(float4*)&a[0] = *(const float4*)&As[kk][rg * 8];
      *(float4*)&a[4] = *(const float4*)&As[kk][rg * 8 + 4];
      *(float4*)&b[0] = *(const float4*)&Bs[0][kk][cg * 4];  // cols cg*8..+3
      *(float4*)&b[4] = *(const float4*)&Bs[1][kk][cg * 4];  // cols cg*8+4..+7
      #pragma unroll
      for (int i = 0; i < 8; i++)
        #pragma unroll
        for (int j = 0; j < 8; j++) acc[i][j] += a[i] * b[j];
    }
    __syncthreads();
  }

  #pragma unroll
  for (int i = 0; i < 8; i++) {
    int gr = row0 + rg * 8 + i;
    if (gr < M) {
      float d = dis[gr];
      // cols cg*8..cg*8+7 -> slice = cg>>3, within-slice offset (cg&7)*8 bf16
      size_t sbase = (size_t)(cg >> 3) * ((size_t)NNP * 64) + (size_t)gr * 64 + (cg & 7) * 8;
      uint4 u;
      u.x = pack2bf(acc[i][0] * d, acc[i][1] * d);
      u.y = pack2bf(acc[i][2] * d, acc[i][3] * d);
      u.z = pack2bf(acc[i][4] * d, acc[i][5] * d);
      u.w = pack2bf(acc[i][6] * d, acc[i][7] * d);
      *(uint4*)(hs16 + sbase) = u;
    }
  }
}

// ---------------- SGEMM 128->32: 128-row tiles, micro 8x2, row-major fp32 out ----------------

__global__ __launch_bounds__(256) void k_gemm32(const float* __restrict__ X, const float* __restrict__ W,
                                                const float* __restrict__ dis, float* __restrict__ H, int M) {
  __shared__ float As[8][128];
  __shared__ float Bs[8][32];
  const int tid = threadIdx.x;
  const int rg = tid >> 4;
  const int cg = tid & 15;
  const int row0 = blockIdx.x * 128;

  float acc[8][2];
  #pragma unroll
  for (int i = 0; i < 8; i++) { acc[i][0] = 0.f; acc[i][1] = 0.f; }

  const int lr = tid >> 1;
  const int lk = (tid & 1) * 4;

  for (int kt = 0; kt < 128; kt += 8) {
    float4 av = make_float4(0.f, 0.f, 0.f, 0.f);
    int gr = row0 + lr;
    if (gr < M) av = *(const float4*)(X + (size_t)gr * 128 + kt + lk);
    As[lk + 0][lr] = av.x; As[lk + 1][lr] = av.y; As[lk + 2][lr] = av.z; As[lk + 3][lr] = av.w;
    int k = tid >> 5, c = tid & 31;
    Bs[k][c] = W[(size_t)(k + kt) * 32 + c];
    __syncthreads();
    #pragma unroll
    for (int kk = 0; kk < 8; kk++) {
      float a[8];
      *(float4*)&a[0] = *(const float4*)&As[kk][rg * 8];
      *(float4*)&a[4] = *(const float4*)&As[kk][rg * 8 + 4];
      float b0 = Bs[kk][cg * 2], b1 = Bs[kk][cg * 2 + 1];
      #pragma unroll
      for (int i = 0; i < 8; i++) { acc[i][0] += a[i] * b0; acc[i][1] += a[i] * b1; }
    }
    __syncthreads();
  }

  #pragma unroll
  for (int i = 0; i < 8; i++) {
    int gr = row0 + rg * 8 + i;
    if (gr < M) {
      float d = dis[gr];
      *(float2*)(H + (size_t)gr * 32 + cg * 2) = make_float2(acc[i][0] * d, acc[i][1] * d);
    }
  }
}

// ---------------- aggregation, layer 0/1: bf16 gather, 128 B rows ----------------
// 2 slices x 64 features x 2 B = 128 B rows (full-line gathers, half the bytes of fp32).
// Wave = 8 nodes x 8 feature-lanes (uint4 = 8 bf16 each). slice = blockIdx & 1.
// Rows padded to x8 with dummy node NN (zero row). fp32 accumulate.

__global__ __launch_bounds__(256) void k_agg128(const unsigned short* __restrict__ Hs,
                                                const float* __restrict__ dis,
                                                const int* __restrict__ rowstart,
                                                const int* __restrict__ csr_src,
                                                const float* __restrict__ bias,
                                                float* __restrict__ out) {
  int slice = blockIdx.x & 1;
  int lane = threadIdx.x & 63;
  int node_sub = lane >> 3;      // 0..7
  int fl = lane & 7;             // 0..7 (8 bf16 = 16 B each)
  int base = node_sub * 8;
  int w = (blockIdx.x >> 1) * 32 + (threadIdx.x >> 6) * 8 + node_sub;
  if (w >= NN) return;
  const unsigned short* __restrict__ S = Hs + (size_t)slice * ((size_t)NNP * 64) + fl * 8;
  float di = dis[w];
  int e0 = rowstart[w], e1 = rowstart[w + 1];   // padded, group-uniform
  float acc[8];
  #pragma unroll
  for (int j = 0; j < 8; j++) acc[j] = 0.f;

  for (int e = e0; e < e1; e += 8) {
    int myIdx = csr_src[e + fl];               // one instr: 64 indices (8/node)
    int s0 = __shfl(myIdx, base + 0), s1 = __shfl(myIdx, base + 1);
    int s2 = __shfl(myIdx, base + 2), s3 = __shfl(myIdx, base + 3);
    int s4 = __shfl(myIdx, base + 4), s5 = __shfl(myIdx, base + 5);
    int s6 = __shfl(myIdx, base + 6), s7 = __shfl(myIdx, base + 7);
    uint4 g0 = *(const uint4*)(S + (size_t)s0 * 64);
    uint4 g1 = *(const uint4*)(S + (size_t)s1 * 64);
    uint4 g2 = *(const uint4*)(S + (size_t)s2 * 64);
    uint4 g3 = *(const uint4*)(S + (size_t)s3 * 64);
    uint4 g4 = *(const uint4*)(S + (size_t)s4 * 64);
    uint4 g5 = *(const uint4*)(S + (size_t)s5 * 64);
    uint4 g6 = *(const uint4*)(S + (size_t)s6 * 64);
    uint4 g7 = *(const uint4*)(S + (size_t)s7 * 64);
    acc[0] += ((bflo(g0.x) + bflo(g1.x)) + (bflo(g2.x) + bflo(g3.x))) + ((bflo(g4.x) + bflo(g5.x)) + (bflo(g6.x) + bflo(g7.x)));
    acc[1] += ((bfhi(g0.x) + bfhi(g1.x)) + (bfhi(g2.x) + bfhi(g3.x))) + ((bfhi(g4.x) + bfhi(g5.x)) + (bfhi(g6.x) + bfhi(g7.x)));
    acc[2] += ((bflo(g0.y) + bflo(g1.y)) + (bflo(g2.y) + bflo(g3.y))) + ((bflo(g4.y) + bflo(g5.y)) + (bflo(g6.y) + bflo(g7.y)));
    acc[3] += ((bfhi(g0.y) + bfhi(g1.y)) + (bfhi(g2.y) + bfhi(g3.y))) + ((bfhi(g4.y) + bfhi(g5.y)) + (bfhi(g6.y) + bfhi(g7.y)));
    acc[4] += ((bflo(g0.z) + bflo(g1.z)) + (bflo(g2.z) + bflo(g3.z))) + ((bflo(g4.z) + bflo(g5.z)) + (bflo(g6.z) + bflo(g7.z)));
    acc[5] += ((bfhi(g0.z) + bfhi(g1.z)) + (bfhi(g2.z) + bfhi(g3.z))) + ((bfhi(g4.z) + bfhi(g5.z)) + (bfhi(g6.z) + bfhi(g7.z)));
    acc[6] += ((bflo(g0.w) + bflo(g1.w)) + (bflo(g2.w) + bflo(g3.w))) + ((bflo(g4.w) + bflo(g5.w)) + (bflo(g6.w) + bflo(g7.w)));
    acc[7] += ((bfhi(g0.w) + bfhi(g1.w)) + (bfhi(g2.w) + bfhi(g3.w))) + ((bfhi(g4.w) + bfhi(g5.w)) + (bfhi(g6.w) + bfhi(g7.w)));
  }
  uint4 sv = *(const uint4*)(S + (size_t)w * 64);
  float selfv[8] = { bflo(sv.x), bfhi(sv.x), bflo(sv.y), bfhi(sv.y),
                     bflo(sv.z), bfhi(sv.z), bflo(sv.w), bfhi(sv.w) };
  int colOff = slice * 64 + fl * 8;
  float4 b0 = *(const float4*)(bias + colOff);
  float4 b1 = *(const float4*)(bias + colOff + 4);
  float4 r0, r1;
  r0.x = (acc[0] + selfv[0]) * di + b0.x;
  r0.y = (acc[1] + selfv[1]) * di + b0.y;
  r0.z = (acc[2] + selfv[2]) * di + b0.z;
  r0.w = (acc[3] + selfv[3]) * di + b0.w;
  r1.x = (acc[4] + selfv[4]) * di + b1.x;
  r1.y = (acc[5] + selfv[5]) * di + b1.y;
  r1.z = (acc[6] + selfv[6]) * di + b1.z;
  r1.w = (acc[7] + selfv[7]) * di + b1.w;
  *(float4*)(out + (size_t)w * 128 + colOff)     = r0;
  *(float4*)(out + (size_t)w * 128 + colOff + 4) = r1;
}

// ---------------- final layer: aggregation + fused log_softmax (fp32) ----------------

__global__ __launch_bounds__(256) void k_agg32lsm(const float* __restrict__ H2,
                                                  const float* __restrict__ dis,
                                                  const int* __restrict__ rowstart,
                                                  const int* __restrict__ csr_src,
                                                  const float* __restrict__ bias,
                                                  float* __restrict__ out) {
  int wave = (blockIdx.x * 256 + threadIdx.x) >> 6;
  int lane = threadIdx.x & 63;
  int half = lane >> 5;
  int l = lane & 31;
  int hbase = half * 32;
  int w = wave * 2 + half;
  if (w >= NN) return;   // NN even: both halves exit together
  const float* __restrict__ S = H2 + l;
  float di = dis[w];
  int e0 = rowstart[w], e1 = rowstart[w + 1];
  float acc = 0.f;
  for (int e = e0; e < e1; e += 8) {
    int myIdx = csr_src[e + (l & 7)];
    int s0 = __shfl(myIdx, hbase + 0), s1 = __shfl(myIdx, hbase + 1);
    int s2 = __shfl(myIdx, hbase + 2), s3 = __shfl(myIdx, hbase + 3);
    int s4 = __shfl(myIdx, hbase + 4), s5 = __shfl(myIdx, hbase + 5);
    int s6 = __shfl(myIdx, hbase + 6), s7 = __shfl(myIdx, hbase + 7);
    float h0 = S[(size_t)s0 * 32], h1 = S[(size_t)s1 * 32];
    float h2v = S[(size_t)s2 * 32], h3 = S[(size_t)s3 * 32];
    float h4 = S[(size_t)s4 * 32], h5 = S[(size_t)s5 * 32];
    float h6 = S[(size_t)s6 * 32], h7 = S[(size_t)s7 * 32];
    acc += ((h0 + h1) + (h2v + h3)) + ((h4 + h5) + (h6 + h7));
  }
  float v = (acc + S[(size_t)w * 32]) * di + bias[l];
  float m = v;
  #pragma unroll
  for (int off = 16; off >= 1; off >>= 1) m = fmaxf(m, __shfl_xor(m, off));
  float ex = expf(v - m);
  float s = ex;
  #pragma unroll
  for (int off = 16; off >= 1; off >>= 1) s += __shfl_xor(s, off);
  out[(size_t)w * 32 + l] = v - m - logf(s);
}

// ---------------- BatchNorm stats + fused BN/ReLU/residual ----------------

__global__ __launch_bounds__(256) void k_bnstats(const float* __restrict__ O, float* __restrict__ gsum,
                                                 float* __restrict__ gsumsq) {
  int tid = threadIdx.x;
  int f = tid & 127;
  int half = tid >> 7;
  float s = 0.f, sq = 0.f;
  for (int r = blockIdx.x * 2 + half; r < NN; r += gridDim.x * 2) {
    float v = O[(size_t)r * 128 + f];
    s += v; sq += v * v;
  }
  __shared__ float sm[256], sm2[256];
  sm[tid] = s; sm2[tid] = sq;
  __syncthreads();
  if (tid < 128) {
    atomicAdd(&gsum[f], sm[tid] + sm[tid + 128]);
    atomicAdd(&gsumsq[f], sm2[tid] + sm2[tid + 128]);
  }
}

// fused BN (inline mu/istd from raw sums) + ReLU + residual
__global__ __launch_bounds__(256) void k_fuse(const float* __restrict__ O, const float* Xin, float* Xout,
                                              const float* __restrict__ gsum, const float* __restrict__ gsumsq,
                                              const float* __restrict__ g, const float* __restrict__ be) {
  int i = blockIdx.x * 256 + threadIdx.x;
  if (i >= NN * 128 / 4) return;
  int f = (i * 4) & 127;
  float4 ov = ((const float4*)O)[i];
  float4 xv = ((const float4*)Xin)[i];
  float4 r;
  const float inv = 1.f / (float)NN;
  #pragma unroll
  for (int j = 0; j < 4; j++) {
    float m = gsum[f + j] * inv;
    float var = gsumsq[f + j] * inv - m * m;
    float istd = rsqrtf(var + 1e-5f);
    float o = (&ov.x)[j];
    float xx = (&xv.x)[j];
    (&r.x)[j] = fmaxf((o - m) * istd * g[f + j] + be[f + j], 0.f) + xx;
  }
  ((float4*)Xout)[i] = r;
}

// ---------------- launch ----------------

extern "C" void kernel_launch(void* const* d_in, const int* in_sizes, int n_in,
                              void* d_out, int out_size, void* d_ws, size_t ws_size,
                              hipStream_t stream) {
  const float* x   = (const float*)d_in[0];
  const int*   ei  = (const int*)d_in[1];
  const float* W0  = (const float*)d_in[2];
  const float* b0  = (const float*)d_in[3];
  const float* g0  = (const float*)d_in[4];
  const float* be0 = (const float*)d_in[5];
  const float* W1  = (const float*)d_in[6];
  const float* b1  = (const float*)d_in[7];
  const float* g1  = (const float*)d_in[8];
  const float* be1 = (const float*)d_in[9];
  const float* W2  = (const float*)d_in[10];
  const float* b2  = (const float*)d_in[11];
  float* out = (float*)d_out;
  const int* srcI = ei;
  const int* dstI = ei + NE;

  char* p = (char*)d_ws;
  auto take = [&](size_t bytes) { char* r = p; p += (bytes + 255) & ~(size_t)255; return (void*)r; };
  int*   deg8     = (int*)take((size_t)8 * NN * 4);
  int*   cursor   = (int*)take(NN * 4);
  int*   degtot   = (int*)take(NN * 4);
  int*   rowstart = (int*)take((NN + 1) * 4);
  int*   blksum   = (int*)take(64 * 4);
  int*   blkoff   = (int*)take(64 * 4);
  int*   binCnt   = (int*)take(8 * 4);
  float* dis      = (float*)take(NN * 4);
  int*   csr      = (int*)take((size_t)NEP * 4);
  int2*  bin      = (int2*)take((size_t)NBKT * BCAP * 8);
  float* gstat    = (float*)take(512 * 4);   // layer0: [0..255], layer1: [256..511]
  unsigned short* hs16 = (unsigned short*)take((size_t)NNP * 128 * 2);  // bf16, 2-slice-major
  float* o        = (float*)take((size_t)NN * 128 * 4);
  float* xA       = (float*)take((size_t)NN * 128 * 4);
  float* h2       = (float*)take((size_t)NNP * 32 * 4);

  k_init<<<(NEP + 255) / 256, 256, 0, stream>>>(deg8, gstat, csr, binCnt);
  k_binA<<<(NE + 1023) / 1024, 1024, 0, stream>>>(srcI, dstI, deg8, binCnt, bin);
  k_scan1<<<NBLK, 1024, 0, stream>>>(deg8, degtot, rowstart, blksum);
  k_scan2<<<1, 64, 0, stream>>>(blksum, blkoff, rowstart);
  k_scan3<<<(NN + 255) / 256, 256, 0, stream>>>(rowstart, blkoff, degtot, cursor, dis, hs16, h2);
  k_fillB<<<512, 256, 0, stream>>>(bin, binCnt, cursor, csr);

  const int aggGrid = ((NN + 31) / 32) * 2;  // 32 nodes/block x 2 slices

  // ---- layer 0 ----
  k_gemm128<<<(NN + 127) / 128, 256, 0, stream>>>(x, W0, dis, hs16, NN);
  k_agg128<<<aggGrid, 256, 0, stream>>>(hs16, dis, rowstart, csr, b0, o);
  k_bnstats<<<1024, 256, 0, stream>>>(o, gstat, gstat + 128);
  k_fuse<<<(NN * 128 / 4 + 255) / 256, 256, 0, stream>>>(o, x, xA, gstat, gstat + 128, g0, be0);

  // ---- layer 1 ----
  k_gemm128<<<(NN + 127) / 128, 256, 0, stream>>>(xA, W1, dis, hs16, NN);
  k_agg128<<<aggGrid, 256, 0, stream>>>(hs16, dis, rowstart, csr, b1, o);
  k_bnstats<<<1024, 256, 0, stream>>>(o, gstat + 256, gstat + 384);
  k_fuse<<<(NN * 128 / 4 + 255) / 256, 256, 0, stream>>>(o, xA, xA, gstat + 256, gstat + 384, g1, be1);

  // ---- final conv + fused aggregation/log_softmax ----
  k_gemm32<<<(NN + 127) / 128, 256, 0, stream>>>(xA, W2, dis, h2, NN);
  k_agg32lsm<<<(NN + 7) / 8, 256, 0, stream>>>(h2, dis, rowstart, csr, b2, out);
}

// Round 13
// 410.001 us; speedup vs baseline: 1.0062x; 1.0062x over previous
//
#include <hip/hip_runtime.h>
#include <math.h>

#define NN 50000
#define NNP (NN + 1)          // +1 dummy zero row per slice
#define NE 800000
#define NEP 1150000           // NE + 7*NN upper bound on padded edge count
#define NBLK 49               // ceil(NN/1024)
#define NBKT 7                // dst-range buckets (d >> 13)
#define BCAP 262144           // per-bucket bin capacity

// bf16 helpers (RNE pack, shift unpack)
__device__ inline unsigned int f2bf(float f) {
  unsigned int u = __float_as_uint(f);
  return (u + 0x7fffu + ((u >> 16) & 1u)) >> 16;
}
__device__ inline unsigned int pack2bf(float lo, float hi) {
  return f2bf(lo) | (f2bf(hi) << 16);
}
__device__ inline float bflo(unsigned int p) { return __uint_as_float(p << 16); }
__device__ inline float bfhi(unsigned int p) { return __uint_as_float(p & 0xffff0000u); }

// ---------------- init: zero deg8/gstat/binCnt, prefill csr with dummy ----------------

__global__ __launch_bounds__(256) void k_init(int* __restrict__ deg8, float* __restrict__ gstat,
                                              int* __restrict__ csr, int* __restrict__ binCnt) {
  int i = blockIdx.x * 256 + threadIdx.x;
  if (i < NEP) csr[i] = NN;
  if (i < 8 * NN) deg8[i] = 0;
  if (i < 512) gstat[i] = 0.f;   // [gsum0|gsq0|gsum1|gsq1] x128
  if (i < NBKT) binCnt[i] = 0;
}

// ---------------- pass A: degree count + dst-range binning ----------------

__global__ __launch_bounds__(1024) void k_binA(const int* __restrict__ src, const int* __restrict__ dst,
                                               int* __restrict__ deg8, int* __restrict__ binCnt,
                                               int2* __restrict__ bin) {
  __shared__ int lcnt[NBKT], lbase[NBKT];
  int tid = threadIdx.x;
  if (tid < NBKT) lcnt[tid] = 0;
  __syncthreads();
  int e = blockIdx.x * 1024 + tid;
  bool act = e < NE;
  int d = 0, s = 0, b = 0, rank = 0;
  if (act) {
    d = dst[e]; s = src[e];
    b = d >> 13;                       // 0..6
    atomicAdd(&deg8[(e & 7) * NN + d], 1);
    rank = atomicAdd(&lcnt[b], 1);
  }
  __syncthreads();
  if (tid < NBKT && lcnt[tid] > 0) lbase[tid] = atomicAdd(&binCnt[tid], lcnt[tid]);
  __syncthreads();
  if (act) bin[(size_t)b * BCAP + lbase[b] + rank] = make_int2(d, s);
}

// scan PADDED total degrees; also emit true total degree
__global__ __launch_bounds__(1024) void k_scan1(const int* __restrict__ deg8, int* __restrict__ degtot,
                                                int* __restrict__ excl, int* __restrict__ blksum) {
  __shared__ int sm[1024];
  int t = threadIdx.x;
  int i = blockIdx.x * 1024 + t;
  int tot = 0;
  if (i < NN) {
    #pragma unroll
    for (int j = 0; j < 8; j++) tot += deg8[j * NN + i];
    degtot[i] = tot;
  }
  int v = (i < NN) ? ((tot + 7) & ~7) : 0;
  sm[t] = v;
  __syncthreads();
  for (int off = 1; off < 1024; off <<= 1) {
    int x = (t >= off) ? sm[t - off] : 0;
    __syncthreads();
    sm[t] += x;
    __syncthreads();
  }
  if (i < NN) excl[i] = sm[t] - v;
  if (t == 1023) blksum[blockIdx.x] = sm[t];
}

__global__ void k_scan2(const int* __restrict__ blksum, int* __restrict__ blkoff,
                        int* __restrict__ rowstart) {
  int t = threadIdx.x;  // 64 threads, one wave
  int orig = (t < NBLK) ? blksum[t] : 0;
  int v = orig;
  #pragma unroll
  for (int off = 1; off < 64; off <<= 1) {
    int u = __shfl_up(v, off);
    if (t >= off) v += u;
  }
  if (t < NBLK) blkoff[t] = v - orig;
  if (t == NBLK - 1) rowstart[NN] = v;  // padded edge total
}

// finalize rowstart; dis; preload cursor; zero bf16 hs pad rows + h2 pad row
__global__ __launch_bounds__(256) void k_scan3(int* __restrict__ excl, const int* __restrict__ blkoff,
                                               const int* __restrict__ degtot, int* __restrict__ cursor,
                                               float* __restrict__ dis,
                                               unsigned short* __restrict__ hs16, float* __restrict__ h2) {
  int i = blockIdx.x * 256 + threadIdx.x;
  if (i < NN) {
    int rs = excl[i] + blkoff[i >> 10];
    excl[i] = rs;
    cursor[i] = rs;
    dis[i] = rsqrtf((float)degtot[i] + 1.0f);
  }
  if (i < 64) {   // hs16 pad row: 2 slices x 64 bf16 = 2 x 32 uints
    int slice = i >> 5, c = i & 31;
    ((unsigned int*)(hs16 + (size_t)slice * ((size_t)NNP * 64) + (size_t)NN * 64))[c] = 0u;
  }
  if (i < 32) h2[(size_t)NN * 32 + i] = 0.f;
}

// ---------------- pass B: scatter within XCD-pinned bucket ----------------

__global__ __launch_bounds__(256) void k_fillB(const int2* __restrict__ bin, const int* __restrict__ binCnt,
                                               int* __restrict__ cursor, int* __restrict__ csr_src) {
  int b = blockIdx.x & 7;
  if (b >= NBKT) return;
  int q = blockIdx.x >> 3;             // 0..63
  int cnt = binCnt[b];
  const int2* __restrict__ B = bin + (size_t)b * BCAP;
  for (int i = q * 256 + threadIdx.x; i < cnt; i += 64 * 256) {
    int2 ds = B[i];
    int p = atomicAdd(&cursor[ds.x], 1);
    csr_src[p] = ds.y;
  }
}

// ---------------- SGEMM 128->128: 64x128 tiles, 4x8 micro, conflict-free split-B ----------
// 782 blocks (~3/CU) restores occupancy; split-B keeps LDS conflict-free.
// hs16[slice][node][64] bf16 (slice = col>>6, stride NNP rows), pre-scaled by dis[row].
// Bs[2][8][68]: Bs[0][k][g*4+j] = W[k][g*8+j], Bs[1][k][g*4+j] = W[k][g*8+4+j].
// b-frag reads: 16 addresses, 16 B stride, contiguous 256 B -> 2-way (free, m136).
// a-frag reads: 16 addresses, 16 B stride -> 2-way (free). 32 FMA per 3 ds_read_b128.

__global__ __launch_bounds__(256) void k_gemm128(const float* __restrict__ X, const float* __restrict__ W,
                                                 const float* __restrict__ dis,
                                                 unsigned short* __restrict__ hs16, int M) {
  __shared__ float As[8][64];
  __shared__ float Bs[2][8][68];
  const int tid = threadIdx.x;
  const int rg = tid >> 4;   // 0..15: 4-row group
  const int cg = tid & 15;   // 0..15: 8-col group
  const int row0 = blockIdx.x * 64;

  float acc[4][8];
  #pragma unroll
  for (int i = 0; i < 4; i++)
    #pragma unroll
    for (int j = 0; j < 8; j++) acc[i][j] = 0.f;

  const int lr = tid >> 2;        // 0..63
  const int lk = (tid & 3) * 2;   // 0,2,4,6
  const int wk = tid >> 5;        // 0..7
  const int wc = tid & 31;        // 0..31

  for (int kt = 0; kt < 128; kt += 8) {
    float2 av = make_float2(0.f, 0.f);
    int gr = row0 + lr;
    if (gr < M) av = *(const float2*)(X + (size_t)gr * 128 + kt + lk);
    As[lk][lr] = av.x; As[lk + 1][lr] = av.y;
    float4 bv = *(const float4*)(W + (size_t)(kt + wk) * 128 + wc * 4);
    int half = wc & 1, bg = wc >> 1;
    Bs[half][wk][bg * 4 + 0] = bv.x;
    Bs[half][wk][bg * 4 + 1] = bv.y;
    Bs[half][wk][bg * 4 + 2] = bv.z;
    Bs[half][wk][bg * 4 + 3] = bv.w;
    __syncthreads();
    #pragma unroll
    for (int kk = 0; kk < 8; kk++) {
      float a[4], b[8];
      *(float4*)&a[0] = *(const float4*)&As[kk][rg * 4];
      *(float4*)&b[0] = *(const float4*)&Bs[0][kk][cg * 4];  // cols cg*8..+3
      *(float4*)&b[4] = *(const float4*)&Bs[1][kk][cg * 4];  // cols cg*8+4..+7
      #pragma unroll
      for (int i = 0; i < 4; i++)
        #pragma unroll
        for (int j = 0; j < 8; j++) acc[i][j] += a[i] * b[j];
    }
    __syncthreads();
  }

  #pragma unroll
  for (int i = 0; i < 4; i++) {
    int gr = row0 + rg * 4 + i;
    if (gr < M) {
      float d = dis[gr];
      // cols cg*8..cg*8+7 -> slice = cg>>3, within-slice offset (cg&7)*8 bf16
      size_t sbase = (size_t)(cg >> 3) * ((size_t)NNP * 64) + (size_t)gr * 64 + (cg & 7) * 8;
      uint4 u;
      u.x = pack2bf(acc[i][0] * d, acc[i][1] * d);
      u.y = pack2bf(acc[i][2] * d, acc[i][3] * d);
      u.z = pack2bf(acc[i][4] * d, acc[i][5] * d);
      u.w = pack2bf(acc[i][6] * d, acc[i][7] * d);
      *(uint4*)(hs16 + sbase) = u;
    }
  }
}

// ---------------- SGEMM 128->32: 128-row tiles, micro 8x2, row-major fp32 out ----------------

__global__ __launch_bounds__(256) void k_gemm32(const float* __restrict__ X, const float* __restrict__ W,
                                                const float* __restrict__ dis, float* __restrict__ H, int M) {
  __shared__ float As[8][128];
  __shared__ float Bs[8][32];
  const int tid = threadIdx.x;
  const int rg = tid >> 4;
  const int cg = tid & 15;
  const int row0 = blockIdx.x * 128;

  float acc[8][2];
  #pragma unroll
  for (int i = 0; i < 8; i++) { acc[i][0] = 0.f; acc[i][1] = 0.f; }

  const int lr = tid >> 1;
  const int lk = (tid & 1) * 4;

  for (int kt = 0; kt < 128; kt += 8) {
    float4 av = make_float4(0.f, 0.f, 0.f, 0.f);
    int gr = row0 + lr;
    if (gr < M) av = *(const float4*)(X + (size_t)gr * 128 + kt + lk);
    As[lk + 0][lr] = av.x; As[lk + 1][lr] = av.y; As[lk + 2][lr] = av.z; As[lk + 3][lr] = av.w;
    int k = tid >> 5, c = tid & 31;
    Bs[k][c] = W[(size_t)(k + kt) * 32 + c];
    __syncthreads();
    #pragma unroll
    for (int kk = 0; kk < 8; kk++) {
      float a[8];
      *(float4*)&a[0] = *(const float4*)&As[kk][rg * 8];
      *(float4*)&a[4] = *(const float4*)&As[kk][rg * 8 + 4];
      float b0 = Bs[kk][cg * 2], b1 = Bs[kk][cg * 2 + 1];
      #pragma unroll
      for (int i = 0; i < 8; i++) { acc[i][0] += a[i] * b0; acc[i][1] += a[i] * b1; }
    }
    __syncthreads();
  }

  #pragma unroll
  for (int i = 0; i < 8; i++) {
    int gr = row0 + rg * 8 + i;
    if (gr < M) {
      float d = dis[gr];
      *(float2*)(H + (size_t)gr * 32 + cg * 2) = make_float2(acc[i][0] * d, acc[i][1] * d);
    }
  }
}

// ---------------- aggregation, layer 0/1: bf16 gather, 128 B rows ----------------
// 2 slices x 64 features x 2 B = 128 B rows (full-line gathers, half the bytes of fp32).
// Wave = 8 nodes x 8 feature-lanes (uint4 = 8 bf16 each). slice = blockIdx & 1.
// Rows padded to x8 with dummy node NN (zero row). fp32 accumulate.

__global__ __launch_bounds__(256) void k_agg128(const unsigned short* __restrict__ Hs,
                                                const float* __restrict__ dis,
                                                const int* __restrict__ rowstart,
                                                const int* __restrict__ csr_src,
                                                const float* __restrict__ bias,
                                                float* __restrict__ out) {
  int slice = blockIdx.x & 1;
  int lane = threadIdx.x & 63;
  int node_sub = lane >> 3;      // 0..7
  int fl = lane & 7;             // 0..7 (8 bf16 = 16 B each)
  int base = node_sub * 8;
  int w = (blockIdx.x >> 1) * 32 + (threadIdx.x >> 6) * 8 + node_sub;
  if (w >= NN) return;
  const unsigned short* __restrict__ S = Hs + (size_t)slice * ((size_t)NNP * 64) + fl * 8;
  float di = dis[w];
  int e0 = rowstart[w], e1 = rowstart[w + 1];   // padded, group-uniform
  float acc[8];
  #pragma unroll
  for (int j = 0; j < 8; j++) acc[j] = 0.f;

  for (int e = e0; e < e1; e += 8) {
    int myIdx = csr_src[e + fl];               // one instr: 64 indices (8/node)
    int s0 = __shfl(myIdx, base + 0), s1 = __shfl(myIdx, base + 1);
    int s2 = __shfl(myIdx, base + 2), s3 = __shfl(myIdx, base + 3);
    int s4 = __shfl(myIdx, base + 4), s5 = __shfl(myIdx, base + 5);
    int s6 = __shfl(myIdx, base + 6), s7 = __shfl(myIdx, base + 7);
    uint4 g0 = *(const uint4*)(S + (size_t)s0 * 64);
    uint4 g1 = *(const uint4*)(S + (size_t)s1 * 64);
    uint4 g2 = *(const uint4*)(S + (size_t)s2 * 64);
    uint4 g3 = *(const uint4*)(S + (size_t)s3 * 64);
    uint4 g4 = *(const uint4*)(S + (size_t)s4 * 64);
    uint4 g5 = *(const uint4*)(S + (size_t)s5 * 64);
    uint4 g6 = *(const uint4*)(S + (size_t)s6 * 64);
    uint4 g7 = *(const uint4*)(S + (size_t)s7 * 64);
    acc[0] += ((bflo(g0.x) + bflo(g1.x)) + (bflo(g2.x) + bflo(g3.x))) + ((bflo(g4.x) + bflo(g5.x)) + (bflo(g6.x) + bflo(g7.x)));
    acc[1] += ((bfhi(g0.x) + bfhi(g1.x)) + (bfhi(g2.x) + bfhi(g3.x))) + ((bfhi(g4.x) + bfhi(g5.x)) + (bfhi(g6.x) + bfhi(g7.x)));
    acc[2] += ((bflo(g0.y) + bflo(g1.y)) + (bflo(g2.y) + bflo(g3.y))) + ((bflo(g4.y) + bflo(g5.y)) + (bflo(g6.y) + bflo(g7.y)));
    acc[3] += ((bfhi(g0.y) + bfhi(g1.y)) + (bfhi(g2.y) + bfhi(g3.y))) + ((bfhi(g4.y) + bfhi(g5.y)) + (bfhi(g6.y) + bfhi(g7.y)));
    acc[4] += ((bflo(g0.z) + bflo(g1.z)) + (bflo(g2.z) + bflo(g3.z))) + ((bflo(g4.z) + bflo(g5.z)) + (bflo(g6.z) + bflo(g7.z)));
    acc[5] += ((bfhi(g0.z) + bfhi(g1.z)) + (bfhi(g2.z) + bfhi(g3.z))) + ((bfhi(g4.z) + bfhi(g5.z)) + (bfhi(g6.z) + bfhi(g7.z)));
    acc[6] += ((bflo(g0.w) + bflo(g1.w)) + (bflo(g2.w) + bflo(g3.w))) + ((bflo(g4.w) + bflo(g5.w)) + (bflo(g6.w) + bflo(g7.w)));
    acc[7] += ((bfhi(g0.w) + bfhi(g1.w)) + (bfhi(g2.w) + bfhi(g3.w))) + ((bfhi(g4.w) + bfhi(g5.w)) + (bfhi(g6.w) + bfhi(g7.w)));
  }
  uint4 sv = *(const uint4*)(S + (size_t)w * 64);
  float selfv[8] = { bflo(sv.x), bfhi(sv.x), bflo(sv.y), bfhi(sv.y),
                     bflo(sv.z), bfhi(sv.z), bflo(sv.w), bfhi(sv.w) };
  int colOff = slice * 64 + fl * 8;
  float4 b0 = *(const float4*)(bias + colOff);
  float4 b1 = *(const float4*)(bias + colOff + 4);
  float4 r0, r1;
  r0.x = (acc[0] + selfv[0]) * di + b0.x;
  r0.y = (acc[1] + selfv[1]) * di + b0.y;
  r0.z = (acc[2] + selfv[2]) * di + b0.z;
  r0.w = (acc[3] + selfv[3]) * di + b0.w;
  r1.x = (acc[4] + selfv[4]) * di + b1.x;
  r1.y = (acc[5] + selfv[5]) * di + b1.y;
  r1.z = (acc[6] + selfv[6]) * di + b1.z;
  r1.w = (acc[7] + selfv[7]) * di + b1.w;
  *(float4*)(out + (size_t)w * 128 + colOff)     = r0;
  *(float4*)(out + (size_t)w * 128 + colOff + 4) = r1;
}

// ---------------- final layer: aggregation + fused log_softmax (fp32) ----------------

__global__ __launch_bounds__(256) void k_agg32lsm(const float* __restrict__ H2,
                                                  const float* __restrict__ dis,
                                                  const int* __restrict__ rowstart,
                                                  const int* __restrict__ csr_src,
                                                  const float* __restrict__ bias,
                                                  float* __restrict__ out) {
  int wave = (blockIdx.x * 256 + threadIdx.x) >> 6;
  int lane = threadIdx.x & 63;
  int half = lane >> 5;
  int l = lane & 31;
  int hbase = half * 32;
  int w = wave * 2 + half;
  if (w >= NN) return;   // NN even: both halves exit together
  const float* __restrict__ S = H2 + l;
  float di = dis[w];
  int e0 = rowstart[w], e1 = rowstart[w + 1];
  float acc = 0.f;
  for (int e = e0; e < e1; e += 8) {
    int myIdx = csr_src[e + (l & 7)];
    int s0 = __shfl(myIdx, hbase + 0), s1 = __shfl(myIdx, hbase + 1);
    int s2 = __shfl(myIdx, hbase + 2), s3 = __shfl(myIdx, hbase + 3);
    int s4 = __shfl(myIdx, hbase + 4), s5 = __shfl(myIdx, hbase + 5);
    int s6 = __shfl(myIdx, hbase + 6), s7 = __shfl(myIdx, hbase + 7);
    float h0 = S[(size_t)s0 * 32], h1 = S[(size_t)s1 * 32];
    float h2v = S[(size_t)s2 * 32], h3 = S[(size_t)s3 * 32];
    float h4 = S[(size_t)s4 * 32], h5 = S[(size_t)s5 * 32];
    float h6 = S[(size_t)s6 * 32], h7 = S[(size_t)s7 * 32];
    acc += ((h0 + h1) + (h2v + h3)) + ((h4 + h5) + (h6 + h7));
  }
  float v = (acc + S[(size_t)w * 32]) * di + bias[l];
  float m = v;
  #pragma unroll
  for (int off = 16; off >= 1; off >>= 1) m = fmaxf(m, __shfl_xor(m, off));
  float ex = expf(v - m);
  float s = ex;
  #pragma unroll
  for (int off = 16; off >= 1; off >>= 1) s += __shfl_xor(s, off);
  out[(size_t)w * 32 + l] = v - m - logf(s);
}

// ---------------- BatchNorm stats + fused BN/ReLU/residual ----------------

__global__ __launch_bounds__(256) void k_bnstats(const float* __restrict__ O, float* __restrict__ gsum,
                                                 float* __restrict__ gsumsq) {
  int tid = threadIdx.x;
  int f = tid & 127;
  int half = tid >> 7;
  float s = 0.f, sq = 0.f;
  for (int r = blockIdx.x * 2 + half; r < NN; r += gridDim.x * 2) {
    float v = O[(size_t)r * 128 + f];
    s += v; sq += v * v;
  }
  __shared__ float sm[256], sm2[256];
  sm[tid] = s; sm2[tid] = sq;
  __syncthreads();
  if (tid < 128) {
    atomicAdd(&gsum[f], sm[tid] + sm[tid + 128]);
    atomicAdd(&gsumsq[f], sm2[tid] + sm2[tid + 128]);
  }
}

// fused BN (inline mu/istd from raw sums) + ReLU + residual
__global__ __launch_bounds__(256) void k_fuse(const float* __restrict__ O, const float* Xin, float* Xout,
                                              const float* __restrict__ gsum, const float* __restrict__ gsumsq,
                                              const float* __restrict__ g, const float* __restrict__ be) {
  int i = blockIdx.x * 256 + threadIdx.x;
  if (i >= NN * 128 / 4) return;
  int f = (i * 4) & 127;
  float4 ov = ((const float4*)O)[i];
  float4 xv = ((const float4*)Xin)[i];
  float4 r;
  const float inv = 1.f / (float)NN;
  #pragma unroll
  for (int j = 0; j < 4; j++) {
    float m = gsum[f + j] * inv;
    float var = gsumsq[f + j] * inv - m * m;
    float istd = rsqrtf(var + 1e-5f);
    float o = (&ov.x)[j];
    float xx = (&xv.x)[j];
    (&r.x)[j] = fmaxf((o - m) * istd * g[f + j] + be[f + j], 0.f) + xx;
  }
  ((float4*)Xout)[i] = r;
}

// ---------------- launch ----------------

extern "C" void kernel_launch(void* const* d_in, const int* in_sizes, int n_in,
                              void* d_out, int out_size, void* d_ws, size_t ws_size,
                              hipStream_t stream) {
  const float* x   = (const float*)d_in[0];
  const int*   ei  = (const int*)d_in[1];
  const float* W0  = (const float*)d_in[2];
  const float* b0  = (const float*)d_in[3];
  const float* g0  = (const float*)d_in[4];
  const float* be0 = (const float*)d_in[5];
  const float* W1  = (const float*)d_in[6];
  const float* b1  = (const float*)d_in[7];
  const float* g1  = (const float*)d_in[8];
  const float* be1 = (const float*)d_in[9];
  const float* W2  = (const float*)d_in[10];
  const float* b2  = (const float*)d_in[11];
  float* out = (float*)d_out;
  const int* srcI = ei;
  const int* dstI = ei + NE;

  char* p = (char*)d_ws;
  auto take = [&](size_t bytes) { char* r = p; p += (bytes + 255) & ~(size_t)255; return (void*)r; };
  int*   deg8     = (int*)take((size_t)8 * NN * 4);
  int*   cursor   = (int*)take(NN * 4);
  int*   degtot   = (int*)take(NN * 4);
  int*   rowstart = (int*)take((NN + 1) * 4);
  int*   blksum   = (int*)take(64 * 4);
  int*   blkoff   = (int*)take(64 * 4);
  int*   binCnt   = (int*)take(8 * 4);
  float* dis      = (float*)take(NN * 4);
  int*   csr      = (int*)take((size_t)NEP * 4);
  int2*  bin      = (int2*)take((size_t)NBKT * BCAP * 8);
  float* gstat    = (float*)take(512 * 4);   // layer0: [0..255], layer1: [256..511]
  unsigned short* hs16 = (unsigned short*)take((size_t)NNP * 128 * 2);  // bf16, 2-slice-major
  float* o        = (float*)take((size_t)NN * 128 * 4);
  float* xA       = (float*)take((size_t)NN * 128 * 4);
  float* h2       = (float*)take((size_t)NNP * 32 * 4);

  k_init<<<(NEP + 255) / 256, 256, 0, stream>>>(deg8, gstat, csr, binCnt);
  k_binA<<<(NE + 1023) / 1024, 1024, 0, stream>>>(srcI, dstI, deg8, binCnt, bin);
  k_scan1<<<NBLK, 1024, 0, stream>>>(deg8, degtot, rowstart, blksum);
  k_scan2<<<1, 64, 0, stream>>>(blksum, blkoff, rowstart);
  k_scan3<<<(NN + 255) / 256, 256, 0, stream>>>(rowstart, blkoff, degtot, cursor, dis, hs16, h2);
  k_fillB<<<512, 256, 0, stream>>>(bin, binCnt, cursor, csr);

  const int aggGrid = ((NN + 31) / 32) * 2;  // 32 nodes/block x 2 slices

  // ---- layer 0 ----
  k_gemm128<<<(NN + 63) / 64, 256, 0, stream>>>(x, W0, dis, hs16, NN);
  k_agg128<<<aggGrid, 256, 0, stream>>>(hs16, dis, rowstart, csr, b0, o);
  k_bnstats<<<1024, 256, 0, stream>>>(o, gstat, gstat + 128);
  k_fuse<<<(NN * 128 / 4 + 255) / 256, 256, 0, stream>>>(o, x, xA, gstat, gstat + 128, g0, be0);

  // ---- layer 1 ----
  k_gemm128<<<(NN + 63) / 64, 256, 0, stream>>>(xA, W1, dis, hs16, NN);
  k_agg128<<<aggGrid, 256, 0, stream>>>(hs16, dis, rowstart, csr, b1, o);
  k_bnstats<<<1024, 256, 0, stream>>>(o, gstat + 256, gstat + 384);
  k_fuse<<<(NN * 128 / 4 + 255) / 256, 256, 0, stream>>>(o, xA, xA, gstat + 256, gstat + 384, g1, be1);

  // ---- final conv + fused aggregation/log_softmax ----
  k_gemm32<<<(NN + 127) / 128, 256, 0, stream>>>(xA, W2, dis, h2, NN);
  k_agg32lsm<<<(NN + 7) / 8, 256, 0, stream>>>(h2, dis, rowstart, csr, b2, out);
}

// Round 15
// 386.160 us; speedup vs baseline: 1.0684x; 1.0617x over previous
//
#include <hip/hip_runtime.h>
#include <math.h>

#define NN 50000
#define NNP (NN + 1)          // +1 dummy zero row per slice
#define NE 800000
#define NEP 1150000           // NE + 7*NN upper bound on padded edge count
#define NBLK 49               // ceil(NN/1024)
#define NBKT 7                // dst-range buckets (d >> 13)
#define BCAP 262144           // per-bucket bin capacity

typedef __attribute__((ext_vector_type(8))) short short8;
typedef __attribute__((ext_vector_type(4))) float float4v;

// bf16 helpers (RNE pack, shift unpack)
__device__ inline unsigned int f2bf(float f) {
  unsigned int u = __float_as_uint(f);
  return (u + 0x7fffu + ((u >> 16) & 1u)) >> 16;
}
__device__ inline unsigned int pack2bf(float lo, float hi) {
  return f2bf(lo) | (f2bf(hi) << 16);
}
__device__ inline float bflo(unsigned int p) { return __uint_as_float(p << 16); }
__device__ inline float bfhi(unsigned int p) { return __uint_as_float(p & 0xffff0000u); }

// ---------------- init: zero deg8/gstat/binCnt, prefill csr with dummy ----------------

__global__ __launch_bounds__(256) void k_init(int* __restrict__ deg8, float* __restrict__ gstat,
                                              int* __restrict__ csr, int* __restrict__ binCnt) {
  int i = blockIdx.x * 256 + threadIdx.x;
  if (i < NEP) csr[i] = NN;
  if (i < 8 * NN) deg8[i] = 0;
  if (i < 512) gstat[i] = 0.f;   // [gsum0|gsq0|gsum1|gsq1] x128
  if (i < NBKT) binCnt[i] = 0;
}

// W -> transposed bf16: wt[n*128+k] = bf16(W[k*128+n]), for W0 and W1
__global__ __launch_bounds__(256) void k_wprep(const float* __restrict__ W0, const float* __restrict__ W1,
                                               unsigned short* __restrict__ wt16) {
  int idx = blockIdx.x * 256 + threadIdx.x;   // 32768 total
  int w = idx >> 14;
  int rem = idx & 16383;
  int k = rem >> 7;
  int n = rem & 127;        // consecutive tid -> consecutive n (coalesced read)
  const float* W = w ? W1 : W0;
  float v = W[k * 128 + n];
  wt16[w * 16384 + n * 128 + k] = (unsigned short)f2bf(v);
}

// ---------------- pass A: degree count + dst-range binning ----------------

__global__ __launch_bounds__(1024) void k_binA(const int* __restrict__ src, const int* __restrict__ dst,
                                               int* __restrict__ deg8, int* __restrict__ binCnt,
                                               int2* __restrict__ bin) {
  __shared__ int lcnt[NBKT], lbase[NBKT];
  int tid = threadIdx.x;
  if (tid < NBKT) lcnt[tid] = 0;
  __syncthreads();
  int e = blockIdx.x * 1024 + tid;
  bool act = e < NE;
  int d = 0, s = 0, b = 0, rank = 0;
  if (act) {
    d = dst[e]; s = src[e];
    b = d >> 13;                       // 0..6
    atomicAdd(&deg8[(e & 7) * NN + d], 1);
    rank = atomicAdd(&lcnt[b], 1);
  }
  __syncthreads();
  if (tid < NBKT && lcnt[tid] > 0) lbase[tid] = atomicAdd(&binCnt[tid], lcnt[tid]);
  __syncthreads();
  if (act) bin[(size_t)b * BCAP + lbase[b] + rank] = make_int2(d, s);
}

// scan PADDED total degrees; also emit true total degree
__global__ __launch_bounds__(1024) void k_scan1(const int* __restrict__ deg8, int* __restrict__ degtot,
                                                int* __restrict__ excl, int* __restrict__ blksum) {
  __shared__ int sm[1024];
  int t = threadIdx.x;
  int i = blockIdx.x * 1024 + t;
  int tot = 0;
  if (i < NN) {
    #pragma unroll
    for (int j = 0; j < 8; j++) tot += deg8[j * NN + i];
    degtot[i] = tot;
  }
  int v = (i < NN) ? ((tot + 7) & ~7) : 0;
  sm[t] = v;
  __syncthreads();
  for (int off = 1; off < 1024; off <<= 1) {
    int x = (t >= off) ? sm[t - off] : 0;
    __syncthreads();
    sm[t] += x;
    __syncthreads();
  }
  if (i < NN) excl[i] = sm[t] - v;
  if (t == 1023) blksum[blockIdx.x] = sm[t];
}

__global__ void k_scan2(const int* __restrict__ blksum, int* __restrict__ blkoff,
                        int* __restrict__ rowstart) {
  int t = threadIdx.x;  // 64 threads, one wave
  int orig = (t < NBLK) ? blksum[t] : 0;
  int v = orig;
  #pragma unroll
  for (int off = 1; off < 64; off <<= 1) {
    int u = __shfl_up(v, off);
    if (t >= off) v += u;
  }
  if (t < NBLK) blkoff[t] = v - orig;
  if (t == NBLK - 1) rowstart[NN] = v;  // padded edge total
}

// finalize rowstart; dis; preload cursor; zero bf16 hs pad rows + h2 pad row
__global__ __launch_bounds__(256) void k_scan3(int* __restrict__ excl, const int* __restrict__ blkoff,
                                               const int* __restrict__ degtot, int* __restrict__ cursor,
                                               float* __restrict__ dis,
                                               unsigned short* __restrict__ hs16, float* __restrict__ h2) {
  int i = blockIdx.x * 256 + threadIdx.x;
  if (i < NN) {
    int rs = excl[i] + blkoff[i >> 10];
    excl[i] = rs;
    cursor[i] = rs;
    dis[i] = rsqrtf((float)degtot[i] + 1.0f);
  }
  if (i < 64) {   // hs16 pad row: 2 slices x 64 bf16 = 2 x 32 uints
    int slice = i >> 5, c = i & 31;
    ((unsigned int*)(hs16 + (size_t)slice * ((size_t)NNP * 64) + (size_t)NN * 64))[c] = 0u;
  }
  if (i < 32) h2[(size_t)NN * 32 + i] = 0.f;
}

// ---------------- pass B: scatter within XCD-pinned bucket ----------------

__global__ __launch_bounds__(256) void k_fillB(const int2* __restrict__ bin, const int* __restrict__ binCnt,
                                               int* __restrict__ cursor, int* __restrict__ csr_src) {
  int b = blockIdx.x & 7;
  if (b >= NBKT) return;
  int q = blockIdx.x >> 3;             // 0..63
  int cnt = binCnt[b];
  const int2* __restrict__ B = bin + (size_t)b * BCAP;
  for (int i = q * 256 + threadIdx.x; i < cnt; i += 64 * 256) {
    int2 ds = B[i];
    int p = atomicAdd(&cursor[ds.x], 1);
    csr_src[p] = ds.y;
  }
}

// ---------------- MFMA bf16 GEMM 128->128: 64-row tiles ----------------
// A-tile [64][136] bf16, Wt-tile [128][136] bf16; full K=128 staged once.
// 4 waves x 8 n-tiles x 4 k-steps of v_mfma_f32_16x16x32_bf16.
// Fragments (m89/m120-verified): A[m=lane&15][k=quad*8+j], B[n=lane&15][k=quad*8+j]
// from transposed W; D col=lane&15, row=quad*4+reg.
// R14 BUG FIX: Bt staging loop was 4 x uint4 (32 shorts) for a 64-short assignment
// -> half of every Bt row was garbage. Now 8 x uint4.

__global__ __launch_bounds__(256) void k_gemm128(const float* __restrict__ X,
                                                 const unsigned short* __restrict__ Wt,
                                                 const float* __restrict__ dis,
                                                 unsigned short* __restrict__ hs16, int M) {
  __shared__ char smem[52224];
  unsigned short* A  = (unsigned short*)smem;            // [64][136]
  unsigned short* Bt = (unsigned short*)(smem + 17408);  // [128][136]
  float* C = (float*)smem;                               // [64][132] (reuse after compute)
  const int tid = threadIdx.x;
  const int row0 = blockIdx.x * 64;

  // stage A: thread t -> row t>>2, 32 cols at (t&3)*32; fp32 -> bf16
  {
    int r = tid >> 2, c0 = (tid & 3) * 32;
    int gr = row0 + r;
    unsigned int* dstp = (unsigned int*)(A + r * 136 + c0);
    #pragma unroll
    for (int i = 0; i < 8; i++) {
      float4 v = make_float4(0.f, 0.f, 0.f, 0.f);
      if (gr < M) v = *(const float4*)(X + (size_t)gr * 128 + c0 + i * 4);
      dstp[i * 2 + 0] = pack2bf(v.x, v.y);
      dstp[i * 2 + 1] = pack2bf(v.z, v.w);
    }
  }
  // stage Bt: thread t -> row t>>1, 64 bf16 at (t&1)*64 = 8 x uint4, coalesced
  {
    int r = tid >> 1, h = (tid & 1) * 64;
    const uint4* src = (const uint4*)(Wt + r * 128 + h);
    uint4* dst = (uint4*)(Bt + r * 136 + h);
    #pragma unroll
    for (int i = 0; i < 8; i++) dst[i] = src[i];
  }
  __syncthreads();

  const int wv = tid >> 6;       // 0..3
  const int l = tid & 63;
  const int lm = l & 15;
  const int lq = l >> 4;

  float4v acc[8];
  #pragma unroll
  for (int j = 0; j < 8; j++) acc[j] = (float4v)(0.f);

  const unsigned short* Arow = A + (wv * 16 + lm) * 136 + lq * 8;
  #pragma unroll
  for (int ks = 0; ks < 4; ks++) {
    short8 af = *(const short8*)(Arow + ks * 32);
    #pragma unroll
    for (int j = 0; j < 8; j++) {
      short8 bf = *(const short8*)(Bt + (j * 16 + lm) * 136 + lq * 8 + ks * 32);
      acc[j] = __builtin_amdgcn_mfma_f32_16x16x32_bf16(af, bf, acc[j], 0, 0, 0);
    }
  }
  __syncthreads();   // done reading A/Bt; reuse as C

  #pragma unroll
  for (int j = 0; j < 8; j++) {
    int col = j * 16 + lm;
    int rbase = wv * 16 + lq * 4;
    #pragma unroll
    for (int r = 0; r < 4; r++) C[(rbase + r) * 132 + col] = acc[j][r];
  }
  __syncthreads();

  // coalesced pack-out: thread t -> row t>>2, cols (t&3)*32..+32, scale by dis, bf16
  {
    int r = tid >> 2, c0 = (tid & 3) * 32;
    int gr = row0 + r;
    if (gr < M) {
      float d = dis[gr];
      int slice = c0 >> 6;
      int cin = c0 & 63;
      unsigned short* dst = hs16 + (size_t)slice * ((size_t)NNP * 64) + (size_t)gr * 64 + cin;
      const float* cp = C + r * 132 + c0;
      #pragma unroll
      for (int i = 0; i < 4; i++) {
        uint4 u;
        u.x = pack2bf(cp[i * 8 + 0] * d, cp[i * 8 + 1] * d);
        u.y = pack2bf(cp[i * 8 + 2] * d, cp[i * 8 + 3] * d);
        u.z = pack2bf(cp[i * 8 + 4] * d, cp[i * 8 + 5] * d);
        u.w = pack2bf(cp[i * 8 + 6] * d, cp[i * 8 + 7] * d);
        *(uint4*)(dst + i * 8) = u;
      }
    }
  }
}

// ---------------- SGEMM 128->32: 128-row tiles, micro 8x2, row-major fp32 out ----------------

__global__ __launch_bounds__(256) void k_gemm32(const float* __restrict__ X, const float* __restrict__ W,
                                                const float* __restrict__ dis, float* __restrict__ H, int M) {
  __shared__ float As[8][128];
  __shared__ float Bs[8][32];
  const int tid = threadIdx.x;
  const int rg = tid >> 4;
  const int cg = tid & 15;
  const int row0 = blockIdx.x * 128;

  float acc[8][2];
  #pragma unroll
  for (int i = 0; i < 8; i++) { acc[i][0] = 0.f; acc[i][1] = 0.f; }

  const int lr = tid >> 1;
  const int lk = (tid & 1) * 4;

  for (int kt = 0; kt < 128; kt += 8) {
    float4 av = make_float4(0.f, 0.f, 0.f, 0.f);
    int gr = row0 + lr;
    if (gr < M) av = *(const float4*)(X + (size_t)gr * 128 + kt + lk);
    As[lk + 0][lr] = av.x; As[lk + 1][lr] = av.y; As[lk + 2][lr] = av.z; As[lk + 3][lr] = av.w;
    int k = tid >> 5, c = tid & 31;
    Bs[k][c] = W[(size_t)(k + kt) * 32 + c];
    __syncthreads();
    #pragma unroll
    for (int kk = 0; kk < 8; kk++) {
      float a[8];
      *(float4*)&a[0] = *(const float4*)&As[kk][rg * 8];
      *(float4*)&a[4] = *(const float4*)&As[kk][rg * 8 + 4];
      float b0 = Bs[kk][cg * 2], b1 = Bs[kk][cg * 2 + 1];
      #pragma unroll
      for (int i = 0; i < 8; i++) { acc[i][0] += a[i] * b0; acc[i][1] += a[i] * b1; }
    }
    __syncthreads();
  }

  #pragma unroll
  for (int i = 0; i < 8; i++) {
    int gr = row0 + rg * 8 + i;
    if (gr < M) {
      float d = dis[gr];
      *(float2*)(H + (size_t)gr * 32 + cg * 2) = make_float2(acc[i][0] * d, acc[i][1] * d);
    }
  }
}

// ---------------- aggregation, layer 0/1: bf16 gather, 128 B rows ----------------

__global__ __launch_bounds__(256) void k_agg128(const unsigned short* __restrict__ Hs,
                                                const float* __restrict__ dis,
                                                const int* __restrict__ rowstart,
                                                const int* __restrict__ csr_src,
                                                const float* __restrict__ bias,
                                                float* __restrict__ out) {
  int slice = blockIdx.x & 1;
  int lane = threadIdx.x & 63;
  int node_sub = lane >> 3;      // 0..7
  int fl = lane & 7;             // 0..7 (8 bf16 = 16 B each)
  int base = node_sub * 8;
  int w = (blockIdx.x >> 1) * 32 + (threadIdx.x >> 6) * 8 + node_sub;
  if (w >= NN) return;
  const unsigned short* __restrict__ S = Hs + (size_t)slice * ((size_t)NNP * 64) + fl * 8;
  float di = dis[w];
  int e0 = rowstart[w], e1 = rowstart[w + 1];   // padded, group-uniform
  float acc[8];
  #pragma unroll
  for (int j = 0; j < 8; j++) acc[j] = 0.f;

  for (int e = e0; e < e1; e += 8) {
    int myIdx = csr_src[e + fl];               // one instr: 64 indices (8/node)
    int s0 = __shfl(myIdx, base + 0), s1 = __shfl(myIdx, base + 1);
    int s2 = __shfl(myIdx, base + 2), s3 = __shfl(myIdx, base + 3);
    int s4 = __shfl(myIdx, base + 4), s5 = __shfl(myIdx, base + 5);
    int s6 = __shfl(myIdx, base + 6), s7 = __shfl(myIdx, base + 7);
    uint4 g0 = *(const uint4*)(S + (size_t)s0 * 64);
    uint4 g1 = *(const uint4*)(S + (size_t)s1 * 64);
    uint4 g2 = *(const uint4*)(S + (size_t)s2 * 64);
    uint4 g3 = *(const uint4*)(S + (size_t)s3 * 64);
    uint4 g4 = *(const uint4*)(S + (size_t)s4 * 64);
    uint4 g5 = *(const uint4*)(S + (size_t)s5 * 64);
    uint4 g6 = *(const uint4*)(S + (size_t)s6 * 64);
    uint4 g7 = *(const uint4*)(S + (size_t)s7 * 64);
    acc[0] += ((bflo(g0.x) + bflo(g1.x)) + (bflo(g2.x) + bflo(g3.x))) + ((bflo(g4.x) + bflo(g5.x)) + (bflo(g6.x) + bflo(g7.x)));
    acc[1] += ((bfhi(g0.x) + bfhi(g1.x)) + (bfhi(g2.x) + bfhi(g3.x))) + ((bfhi(g4.x) + bfhi(g5.x)) + (bfhi(g6.x) + bfhi(g7.x)));
    acc[2] += ((bflo(g0.y) + bflo(g1.y)) + (bflo(g2.y) + bflo(g3.y))) + ((bflo(g4.y) + bflo(g5.y)) + (bflo(g6.y) + bflo(g7.y)));
    acc[3] += ((bfhi(g0.y) + bfhi(g1.y)) + (bfhi(g2.y) + bfhi(g3.y))) + ((bfhi(g4.y) + bfhi(g5.y)) + (bfhi(g6.y) + bfhi(g7.y)));
    acc[4] += ((bflo(g0.z) + bflo(g1.z)) + (bflo(g2.z) + bflo(g3.z))) + ((bflo(g4.z) + bflo(g5.z)) + (bflo(g6.z) + bflo(g7.z)));
    acc[5] += ((bfhi(g0.z) + bfhi(g1.z)) + (bfhi(g2.z) + bfhi(g3.z))) + ((bfhi(g4.z) + bfhi(g5.z)) + (bfhi(g6.z) + bfhi(g7.z)));
    acc[6] += ((bflo(g0.w) + bflo(g1.w)) + (bflo(g2.w) + bflo(g3.w))) + ((bflo(g4.w) + bflo(g5.w)) + (bflo(g6.w) + bflo(g7.w)));
    acc[7] += ((bfhi(g0.w) + bfhi(g1.w)) + (bfhi(g2.w) + bfhi(g3.w))) + ((bfhi(g4.w) + bfhi(g5.w)) + (bfhi(g6.w) + bfhi(g7.w)));
  }
  uint4 sv = *(const uint4*)(S + (size_t)w * 64);
  float selfv[8] = { bflo(sv.x), bfhi(sv.x), bflo(sv.y), bfhi(sv.y),
                     bflo(sv.z), bfhi(sv.z), bflo(sv.w), bfhi(sv.w) };
  int colOff = slice * 64 + fl * 8;
  float4 b0 = *(const float4*)(bias + colOff);
  float4 b1 = *(const float4*)(bias + colOff + 4);
  float4 r0, r1;
  r0.x = (acc[0] + selfv[0]) * di + b0.x;
  r0.y = (acc[1] + selfv[1]) * di + b0.y;
  r0.z = (acc[2] + selfv[2]) * di + b0.z;
  r0.w = (acc[3] + selfv[3]) * di + b0.w;
  r1.x = (acc[4] + selfv[4]) * di + b1.x;
  r1.y = (acc[5] + selfv[5]) * di + b1.y;
  r1.z = (acc[6] + selfv[6]) * di + b1.z;
  r1.w = (acc[7] + selfv[7]) * di + b1.w;
  *(float4*)(out + (size_t)w * 128 + colOff)     = r0;
  *(float4*)(out + (size_t)w * 128 + colOff + 4) = r1;
}

// ---------------- final layer: aggregation + fused log_softmax (fp32) ----------------

__global__ __launch_bounds__(256) void k_agg32lsm(const float* __restrict__ H2,
                                                  const float* __restrict__ dis,
                                                  const int* __restrict__ rowstart,
                                                  const int* __restrict__ csr_src,
                                                  const float* __restrict__ bias,
                                                  float* __restrict__ out) {
  int wave = (blockIdx.x * 256 + threadIdx.x) >> 6;
  int lane = threadIdx.x & 63;
  int half = lane >> 5;
  int l = lane & 31;
  int hbase = half * 32;
  int w = wave * 2 + half;
  if (w >= NN) return;   // NN even: both halves exit together
  const float* __restrict__ S = H2 + l;
  float di = dis[w];
  int e0 = rowstart[w], e1 = rowstart[w + 1];
  float acc = 0.f;
  for (int e = e0; e < e1; e += 8) {
    int myIdx = csr_src[e + (l & 7)];
    int s0 = __shfl(myIdx, hbase + 0), s1 = __shfl(myIdx, hbase + 1);
    int s2 = __shfl(myIdx, hbase + 2), s3 = __shfl(myIdx, hbase + 3);
    int s4 = __shfl(myIdx, hbase + 4), s5 = __shfl(myIdx, hbase + 5);
    int s6 = __shfl(myIdx, hbase + 6), s7 = __shfl(myIdx, hbase + 7);
    float h0 = S[(size_t)s0 * 32], h1 = S[(size_t)s1 * 32];
    float h2v = S[(size_t)s2 * 32], h3 = S[(size_t)s3 * 32];
    float h4 = S[(size_t)s4 * 32], h5 = S[(size_t)s5 * 32];
    float h6 = S[(size_t)s6 * 32], h7 = S[(size_t)s7 * 32];
    acc += ((h0 + h1) + (h2v + h3)) + ((h4 + h5) + (h6 + h7));
  }
  float v = (acc + S[(size_t)w * 32]) * di + bias[l];
  float m = v;
  #pragma unroll
  for (int off = 16; off >= 1; off >>= 1) m = fmaxf(m, __shfl_xor(m, off));
  float ex = expf(v - m);
  float s = ex;
  #pragma unroll
  for (int off = 16; off >= 1; off >>= 1) s += __shfl_xor(s, off);
  out[(size_t)w * 32 + l] = v - m - logf(s);
}

// ---------------- BatchNorm stats + fused BN/ReLU/residual ----------------

__global__ __launch_bounds__(256) void k_bnstats(const float* __restrict__ O, float* __restrict__ gsum,
                                                 float* __restrict__ gsumsq) {
  int tid = threadIdx.x;
  int f = tid & 127;
  int half = tid >> 7;
  float s = 0.f, sq = 0.f;
  for (int r = blockIdx.x * 2 + half; r < NN; r += gridDim.x * 2) {
    float v = O[(size_t)r * 128 + f];
    s += v; sq += v * v;
  }
  __shared__ float sm[256], sm2[256];
  sm[tid] = s; sm2[tid] = sq;
  __syncthreads();
  if (tid < 128) {
    atomicAdd(&gsum[f], sm[tid] + sm[tid + 128]);
    atomicAdd(&gsumsq[f], sm2[tid] + sm2[tid + 128]);
  }
}

// fused BN (inline mu/istd from raw sums) + ReLU + residual
__global__ __launch_bounds__(256) void k_fuse(const float* __restrict__ O, const float* Xin, float* Xout,
                                              const float* __restrict__ gsum, const float* __restrict__ gsumsq,
                                              const float* __restrict__ g, const float* __restrict__ be) {
  int i = blockIdx.x * 256 + threadIdx.x;
  if (i >= NN * 128 / 4) return;
  int f = (i * 4) & 127;
  float4 ov = ((const float4*)O)[i];
  float4 xv = ((const float4*)Xin)[i];
  float4 r;
  const float inv = 1.f / (float)NN;
  #pragma unroll
  for (int j = 0; j < 4; j++) {
    float m = gsum[f + j] * inv;
    float var = gsumsq[f + j] * inv - m * m;
    float istd = rsqrtf(var + 1e-5f);
    float o = (&ov.x)[j];
    float xx = (&xv.x)[j];
    (&r.x)[j] = fmaxf((o - m) * istd * g[f + j] + be[f + j], 0.f) + xx;
  }
  ((float4*)Xout)[i] = r;
}

// ---------------- launch ----------------

extern "C" void kernel_launch(void* const* d_in, const int* in_sizes, int n_in,
                              void* d_out, int out_size, void* d_ws, size_t ws_size,
                              hipStream_t stream) {
  const float* x   = (const float*)d_in[0];
  const int*   ei  = (const int*)d_in[1];
  const float* W0  = (const float*)d_in[2];
  const float* b0  = (const float*)d_in[3];
  const float* g0  = (const float*)d_in[4];
  const float* be0 = (const float*)d_in[5];
  const float* W1  = (const float*)d_in[6];
  const float* b1  = (const float*)d_in[7];
  const float* g1  = (const float*)d_in[8];
  const float* be1 = (const float*)d_in[9];
  const float* W2  = (const float*)d_in[10];
  const float* b2  = (const float*)d_in[11];
  float* out = (float*)d_out;
  const int* srcI = ei;
  const int* dstI = ei + NE;

  char* p = (char*)d_ws;
  auto take = [&](size_t bytes) { char* r = p; p += (bytes + 255) & ~(size_t)255; return (void*)r; };
  int*   deg8     = (int*)take((size_t)8 * NN * 4);
  int*   cursor   = (int*)take(NN * 4);
  int*   degtot   = (int*)take(NN * 4);
  int*   rowstart = (int*)take((NN + 1) * 4);
  int*   blksum   = (int*)take(64 * 4);
  int*   blkoff   = (int*)take(64 * 4);
  int*   binCnt   = (int*)take(8 * 4);
  float* dis      = (float*)take(NN * 4);
  int*   csr      = (int*)take((size_t)NEP * 4);
  int2*  bin      = (int2*)take((size_t)NBKT * BCAP * 8);
  float* gstat    = (float*)take(512 * 4);   // layer0: [0..255], layer1: [256..511]
  unsigned short* wt16 = (unsigned short*)take(2 * 16384 * 2);  // W0^T, W1^T bf16
  unsigned short* hs16 = (unsigned short*)take((size_t)NNP * 128 * 2);  // bf16, 2-slice-major
  float* o        = (float*)take((size_t)NN * 128 * 4);
  float* xA       = (float*)take((size_t)NN * 128 * 4);
  float* h2       = (float*)take((size_t)NNP * 32 * 4);

  k_init<<<(NEP + 255) / 256, 256, 0, stream>>>(deg8, gstat, csr, binCnt);
  k_wprep<<<128, 256, 0, stream>>>(W0, W1, wt16);
  k_binA<<<(NE + 1023) / 1024, 1024, 0, stream>>>(srcI, dstI, deg8, binCnt, bin);
  k_scan1<<<NBLK, 1024, 0, stream>>>(deg8, degtot, rowstart, blksum);
  k_scan2<<<1, 64, 0, stream>>>(blksum, blkoff, rowstart);
  k_scan3<<<(NN + 255) / 256, 256, 0, stream>>>(rowstart, blkoff, degtot, cursor, dis, hs16, h2);
  k_fillB<<<512, 256, 0, stream>>>(bin, binCnt, cursor, csr);

  const int aggGrid = ((NN + 31) / 32) * 2;  // 32 nodes/block x 2 slices

  // ---- layer 0 ----
  k_gemm128<<<(NN + 63) / 64, 256, 0, stream>>>(x, wt16, dis, hs16, NN);
  k_agg128<<<aggGrid, 256, 0, stream>>>(hs16, dis, rowstart, csr, b0, o);
  k_bnstats<<<1024, 256, 0, stream>>>(o, gstat, gstat + 128);
  k_fuse<<<(NN * 128 / 4 + 255) / 256, 256, 0, stream>>>(o, x, xA, gstat, gstat + 128, g0, be0);

  // ---- layer 1 ----
  k_gemm128<<<(NN + 63) / 64, 256, 0, stream>>>(xA, wt16 + 16384, dis, hs16, NN);
  k_agg128<<<aggGrid, 256, 0, stream>>>(hs16, dis, rowstart, csr, b1, o);
  k_bnstats<<<1024, 256, 0, stream>>>(o, gstat + 256, gstat + 384);
  k_fuse<<<(NN * 128 / 4 + 255) / 256, 256, 0, stream>>>(o, xA, xA, gstat + 256, gstat + 384, g1, be1);

  // ---- final conv + fused aggregation/log_softmax ----
  k_gemm32<<<(NN + 127) / 128, 256, 0, stream>>>(xA, W2, dis, h2, NN);
  k_agg32lsm<<<(NN + 7) / 8, 256, 0, stream>>>(h2, dis, rowstart, csr, b2, out);
}

// Round 16
// 379.287 us; speedup vs baseline: 1.0877x; 1.0181x over previous
//
#include <hip/hip_runtime.h>
#include <math.h>

#define NN 50000
#define NNP (NN + 1)          // +1 dummy zero row per slice
#define NE 800000
#define NEP 1150000           // NE + 7*NN upper bound on padded edge count
#define NBLK 49               // ceil(NN/1024)
#define NBKT 7                // dst-range buckets (d >> 13)
#define BCAP 262144           // per-bucket bin capacity

typedef __attribute__((ext_vector_type(8))) short short8;
typedef __attribute__((ext_vector_type(4))) float float4v;

// bf16 helpers (RNE pack, shift unpack)
__device__ inline unsigned int f2bf(float f) {
  unsigned int u = __float_as_uint(f);
  return (u + 0x7fffu + ((u >> 16) & 1u)) >> 16;
}
__device__ inline unsigned int pack2bf(float lo, float hi) {
  return f2bf(lo) | (f2bf(hi) << 16);
}
__device__ inline float bflo(unsigned int p) { return __uint_as_float(p << 16); }
__device__ inline float bfhi(unsigned int p) { return __uint_as_float(p & 0xffff0000u); }

// ---------------- init: zero deg8/gstat/binCnt, prefill csr, W->bf16^T prep ----------------

__global__ __launch_bounds__(256) void k_init(int* __restrict__ deg8, float* __restrict__ gstat,
                                              int* __restrict__ csr, int* __restrict__ binCnt,
                                              const float* __restrict__ W0, const float* __restrict__ W1,
                                              const float* __restrict__ W2,
                                              unsigned short* __restrict__ wt16) {
  int i = blockIdx.x * 256 + threadIdx.x;
  if (i < NEP) csr[i] = NN;
  if (i < 8 * NN) deg8[i] = 0;
  if (i < 512) gstat[i] = 0.f;   // [gsum0|gsq0|gsum1|gsq1] x128
  if (i < NBKT) binCnt[i] = 0;
  if (i < 32768) {               // W0^T, W1^T bf16
    int w = i >> 14;
    int rem = i & 16383;
    int k = rem >> 7;
    int n = rem & 127;
    const float* W = w ? W1 : W0;
    wt16[w * 16384 + n * 128 + k] = (unsigned short)f2bf(W[k * 128 + n]);
  } else if (i < 36864) {        // W2^T bf16 (32x128)
    int idx = i - 32768;
    int n = idx >> 7;
    int k = idx & 127;
    wt16[32768 + n * 128 + k] = (unsigned short)f2bf(W2[k * 32 + n]);
  }
}

// ---------------- pass A: degree count + dst-range binning ----------------

__global__ __launch_bounds__(1024) void k_binA(const int* __restrict__ src, const int* __restrict__ dst,
                                               int* __restrict__ deg8, int* __restrict__ binCnt,
                                               int2* __restrict__ bin) {
  __shared__ int lcnt[NBKT], lbase[NBKT];
  int tid = threadIdx.x;
  if (tid < NBKT) lcnt[tid] = 0;
  __syncthreads();
  int e = blockIdx.x * 1024 + tid;
  bool act = e < NE;
  int d = 0, s = 0, b = 0, rank = 0;
  if (act) {
    d = dst[e]; s = src[e];
    b = d >> 13;                       // 0..6
    atomicAdd(&deg8[(e & 7) * NN + d], 1);
    rank = atomicAdd(&lcnt[b], 1);
  }
  __syncthreads();
  if (tid < NBKT && lcnt[tid] > 0) lbase[tid] = atomicAdd(&binCnt[tid], lcnt[tid]);
  __syncthreads();
  if (act) bin[(size_t)b * BCAP + lbase[b] + rank] = make_int2(d, s);
}

// scan PADDED total degrees; also emit true total degree
__global__ __launch_bounds__(1024) void k_scan1(const int* __restrict__ deg8, int* __restrict__ degtot,
                                                int* __restrict__ excl, int* __restrict__ blksum) {
  __shared__ int sm[1024];
  int t = threadIdx.x;
  int i = blockIdx.x * 1024 + t;
  int tot = 0;
  if (i < NN) {
    #pragma unroll
    for (int j = 0; j < 8; j++) tot += deg8[j * NN + i];
    degtot[i] = tot;
  }
  int v = (i < NN) ? ((tot + 7) & ~7) : 0;
  sm[t] = v;
  __syncthreads();
  for (int off = 1; off < 1024; off <<= 1) {
    int x = (t >= off) ? sm[t - off] : 0;
    __syncthreads();
    sm[t] += x;
    __syncthreads();
  }
  if (i < NN) excl[i] = sm[t] - v;
  if (t == 1023) blksum[blockIdx.x] = sm[t];
}

__global__ void k_scan2(const int* __restrict__ blksum, int* __restrict__ blkoff,
                        int* __restrict__ rowstart) {
  int t = threadIdx.x;  // 64 threads, one wave
  int orig = (t < NBLK) ? blksum[t] : 0;
  int v = orig;
  #pragma unroll
  for (int off = 1; off < 64; off <<= 1) {
    int u = __shfl_up(v, off);
    if (t >= off) v += u;
  }
  if (t < NBLK) blkoff[t] = v - orig;
  if (t == NBLK - 1) rowstart[NN] = v;  // padded edge total
}

// finalize rowstart; dis; preload cursor; zero bf16 hs pad rows + h2 pad row
__global__ __launch_bounds__(256) void k_scan3(int* __restrict__ excl, const int* __restrict__ blkoff,
                                               const int* __restrict__ degtot, int* __restrict__ cursor,
                                               float* __restrict__ dis,
                                               unsigned short* __restrict__ hs16, float* __restrict__ h2) {
  int i = blockIdx.x * 256 + threadIdx.x;
  if (i < NN) {
    int rs = excl[i] + blkoff[i >> 10];
    excl[i] = rs;
    cursor[i] = rs;
    dis[i] = rsqrtf((float)degtot[i] + 1.0f);
  }
  if (i < 64) {   // hs16 pad row: 2 slices x 64 bf16 = 2 x 32 uints
    int slice = i >> 5, c = i & 31;
    ((unsigned int*)(hs16 + (size_t)slice * ((size_t)NNP * 64) + (size_t)NN * 64))[c] = 0u;
  }
  if (i < 32) h2[(size_t)NN * 32 + i] = 0.f;
}

// ---------------- pass B: scatter within XCD-pinned bucket ----------------

__global__ __launch_bounds__(256) void k_fillB(const int2* __restrict__ bin, const int* __restrict__ binCnt,
                                               int* __restrict__ cursor, int* __restrict__ csr_src) {
  int b = blockIdx.x & 7;
  if (b >= NBKT) return;
  int q = blockIdx.x >> 3;             // 0..63
  int cnt = binCnt[b];
  const int2* __restrict__ B = bin + (size_t)b * BCAP;
  for (int i = q * 256 + threadIdx.x; i < cnt; i += 64 * 256) {
    int2 ds = B[i];
    int p = atomicAdd(&cursor[ds.x], 1);
    csr_src[p] = ds.y;
  }
}

// ---------------- MFMA bf16 GEMM 128->128: 64-row tiles (R15-proven) ----------------

__global__ __launch_bounds__(256) void k_gemm128(const float* __restrict__ X,
                                                 const unsigned short* __restrict__ Wt,
                                                 const float* __restrict__ dis,
                                                 unsigned short* __restrict__ hs16, int M) {
  __shared__ char smem[52224];
  unsigned short* A  = (unsigned short*)smem;            // [64][136]
  unsigned short* Bt = (unsigned short*)(smem + 17408);  // [128][136]
  float* C = (float*)smem;                               // [64][132] (reuse after compute)
  const int tid = threadIdx.x;
  const int row0 = blockIdx.x * 64;

  // stage A: thread t -> row t>>2, 32 cols at (t&3)*32; fp32 -> bf16
  {
    int r = tid >> 2, c0 = (tid & 3) * 32;
    int gr = row0 + r;
    unsigned int* dstp = (unsigned int*)(A + r * 136 + c0);
    #pragma unroll
    for (int i = 0; i < 8; i++) {
      float4 v = make_float4(0.f, 0.f, 0.f, 0.f);
      if (gr < M) v = *(const float4*)(X + (size_t)gr * 128 + c0 + i * 4);
      dstp[i * 2 + 0] = pack2bf(v.x, v.y);
      dstp[i * 2 + 1] = pack2bf(v.z, v.w);
    }
  }
  // stage Bt: thread t -> row t>>1, 64 bf16 at (t&1)*64 = 8 x uint4
  {
    int r = tid >> 1, h = (tid & 1) * 64;
    const uint4* src = (const uint4*)(Wt + r * 128 + h);
    uint4* dst = (uint4*)(Bt + r * 136 + h);
    #pragma unroll
    for (int i = 0; i < 8; i++) dst[i] = src[i];
  }
  __syncthreads();

  const int wv = tid >> 6;       // 0..3
  const int l = tid & 63;
  const int lm = l & 15;
  const int lq = l >> 4;

  float4v acc[8];
  #pragma unroll
  for (int j = 0; j < 8; j++) acc[j] = (float4v)(0.f);

  const unsigned short* Arow = A + (wv * 16 + lm) * 136 + lq * 8;
  #pragma unroll
  for (int ks = 0; ks < 4; ks++) {
    short8 af = *(const short8*)(Arow + ks * 32);
    #pragma unroll
    for (int j = 0; j < 8; j++) {
      short8 bf = *(const short8*)(Bt + (j * 16 + lm) * 136 + lq * 8 + ks * 32);
      acc[j] = __builtin_amdgcn_mfma_f32_16x16x32_bf16(af, bf, acc[j], 0, 0, 0);
    }
  }
  __syncthreads();   // done reading A/Bt; reuse as C

  #pragma unroll
  for (int j = 0; j < 8; j++) {
    int col = j * 16 + lm;
    int rbase = wv * 16 + lq * 4;
    #pragma unroll
    for (int r = 0; r < 4; r++) C[(rbase + r) * 132 + col] = acc[j][r];
  }
  __syncthreads();

  // coalesced pack-out: thread t -> row t>>2, cols (t&3)*32..+32, scale by dis, bf16
  {
    int r = tid >> 2, c0 = (tid & 3) * 32;
    int gr = row0 + r;
    if (gr < M) {
      float d = dis[gr];
      int slice = c0 >> 6;
      int cin = c0 & 63;
      unsigned short* dst = hs16 + (size_t)slice * ((size_t)NNP * 64) + (size_t)gr * 64 + cin;
      const float* cp = C + r * 132 + c0;
      #pragma unroll
      for (int i = 0; i < 4; i++) {
        uint4 u;
        u.x = pack2bf(cp[i * 8 + 0] * d, cp[i * 8 + 1] * d);
        u.y = pack2bf(cp[i * 8 + 2] * d, cp[i * 8 + 3] * d);
        u.z = pack2bf(cp[i * 8 + 4] * d, cp[i * 8 + 5] * d);
        u.w = pack2bf(cp[i * 8 + 6] * d, cp[i * 8 + 7] * d);
        *(uint4*)(dst + i * 8) = u;
      }
    }
  }
}

// ---------------- MFMA bf16 GEMM 128->32: 64-row tiles, fp32 out ----------------
// Mirrors k_gemm128: A [64][136] bf16, W2t [32][136] bf16, 2 n-tiles x 4 k-steps.

__global__ __launch_bounds__(256) void k_gemm32m(const float* __restrict__ X,
                                                 const unsigned short* __restrict__ Wt2,
                                                 const float* __restrict__ dis,
                                                 float* __restrict__ H, int M) {
  __shared__ char smem[26112];
  unsigned short* A   = (unsigned short*)smem;            // [64][136]
  unsigned short* Bt2 = (unsigned short*)(smem + 17408);  // [32][136]
  float* C = (float*)smem;                                // [64][36] (reuse)
  const int tid = threadIdx.x;
  const int row0 = blockIdx.x * 64;

  // stage A (same as gemm128)
  {
    int r = tid >> 2, c0 = (tid & 3) * 32;
    int gr = row0 + r;
    unsigned int* dstp = (unsigned int*)(A + r * 136 + c0);
    #pragma unroll
    for (int i = 0; i < 8; i++) {
      float4 v = make_float4(0.f, 0.f, 0.f, 0.f);
      if (gr < M) v = *(const float4*)(X + (size_t)gr * 128 + c0 + i * 4);
      dstp[i * 2 + 0] = pack2bf(v.x, v.y);
      dstp[i * 2 + 1] = pack2bf(v.z, v.w);
    }
  }
  // stage Bt2: thread t -> row t>>3 (0..31), 16 bf16 at (t&7)*16 = 2 x uint4
  {
    int r = tid >> 3, h = (tid & 7) * 16;
    const uint4* src = (const uint4*)(Wt2 + r * 128 + h);
    uint4* dst = (uint4*)(Bt2 + r * 136 + h);
    dst[0] = src[0];
    dst[1] = src[1];
  }
  __syncthreads();

  const int wv = tid >> 6;
  const int l = tid & 63;
  const int lm = l & 15;
  const int lq = l >> 4;

  float4v acc[2];
  acc[0] = (float4v)(0.f);
  acc[1] = (float4v)(0.f);

  const unsigned short* Arow = A + (wv * 16 + lm) * 136 + lq * 8;
  #pragma unroll
  for (int ks = 0; ks < 4; ks++) {
    short8 af = *(const short8*)(Arow + ks * 32);
    #pragma unroll
    for (int j = 0; j < 2; j++) {
      short8 bf = *(const short8*)(Bt2 + (j * 16 + lm) * 136 + lq * 8 + ks * 32);
      acc[j] = __builtin_amdgcn_mfma_f32_16x16x32_bf16(af, bf, acc[j], 0, 0, 0);
    }
  }
  __syncthreads();   // reuse smem as C

  #pragma unroll
  for (int j = 0; j < 2; j++) {
    int col = j * 16 + lm;
    int rbase = wv * 16 + lq * 4;
    #pragma unroll
    for (int r = 0; r < 4; r++) C[(rbase + r) * 36 + col] = acc[j][r];
  }
  __syncthreads();

  // pack-out: thread t -> row t>>2, 8 cols at (t&3)*8, fp32 scaled by dis
  {
    int r = tid >> 2, c0 = (tid & 3) * 8;
    int gr = row0 + r;
    if (gr < M) {
      float d = dis[gr];
      const float* cp = C + r * 36 + c0;
      float* dst = H + (size_t)gr * 32 + c0;
      float4 v0 = make_float4(cp[0] * d, cp[1] * d, cp[2] * d, cp[3] * d);
      float4 v1 = make_float4(cp[4] * d, cp[5] * d, cp[6] * d, cp[7] * d);
      *(float4*)(dst)     = v0;
      *(float4*)(dst + 4) = v1;
    }
  }
}

// ---------------- aggregation, layer 0/1: bf16 gather, 128 B rows ----------------

__global__ __launch_bounds__(256) void k_agg128(const unsigned short* __restrict__ Hs,
                                                const float* __restrict__ dis,
                                                const int* __restrict__ rowstart,
                                                const int* __restrict__ csr_src,
                                                const float* __restrict__ bias,
                                                float* __restrict__ out) {
  int slice = blockIdx.x & 1;
  int lane = threadIdx.x & 63;
  int node_sub = lane >> 3;      // 0..7
  int fl = lane & 7;             // 0..7 (8 bf16 = 16 B each)
  int base = node_sub * 8;
  int w = (blockIdx.x >> 1) * 32 + (threadIdx.x >> 6) * 8 + node_sub;
  if (w >= NN) return;
  const unsigned short* __restrict__ S = Hs + (size_t)slice * ((size_t)NNP * 64) + fl * 8;
  float di = dis[w];
  int e0 = rowstart[w], e1 = rowstart[w + 1];   // padded, group-uniform
  float acc[8];
  #pragma unroll
  for (int j = 0; j < 8; j++) acc[j] = 0.f;

  for (int e = e0; e < e1; e += 8) {
    int myIdx = csr_src[e + fl];               // one instr: 64 indices (8/node)
    int s0 = __shfl(myIdx, base + 0), s1 = __shfl(myIdx, base + 1);
    int s2 = __shfl(myIdx, base + 2), s3 = __shfl(myIdx, base + 3);
    int s4 = __shfl(myIdx, base + 4), s5 = __shfl(myIdx, base + 5);
    int s6 = __shfl(myIdx, base + 6), s7 = __shfl(myIdx, base + 7);
    uint4 g0 = *(const uint4*)(S + (size_t)s0 * 64);
    uint4 g1 = *(const uint4*)(S + (size_t)s1 * 64);
    uint4 g2 = *(const uint4*)(S + (size_t)s2 * 64);
    uint4 g3 = *(const uint4*)(S + (size_t)s3 * 64);
    uint4 g4 = *(const uint4*)(S + (size_t)s4 * 64);
    uint4 g5 = *(const uint4*)(S + (size_t)s5 * 64);
    uint4 g6 = *(const uint4*)(S + (size_t)s6 * 64);
    uint4 g7 = *(const uint4*)(S + (size_t)s7 * 64);
    acc[0] += ((bflo(g0.x) + bflo(g1.x)) + (bflo(g2.x) + bflo(g3.x))) + ((bflo(g4.x) + bflo(g5.x)) + (bflo(g6.x) + bflo(g7.x)));
    acc[1] += ((bfhi(g0.x) + bfhi(g1.x)) + (bfhi(g2.x) + bfhi(g3.x))) + ((bfhi(g4.x) + bfhi(g5.x)) + (bfhi(g6.x) + bfhi(g7.x)));
    acc[2] += ((bflo(g0.y) + bflo(g1.y)) + (bflo(g2.y) + bflo(g3.y))) + ((bflo(g4.y) + bflo(g5.y)) + (bflo(g6.y) + bflo(g7.y)));
    acc[3] += ((bfhi(g0.y) + bfhi(g1.y)) + (bfhi(g2.y) + bfhi(g3.y))) + ((bfhi(g4.y) + bfhi(g5.y)) + (bfhi(g6.y) + bfhi(g7.y)));
    acc[4] += ((bflo(g0.z) + bflo(g1.z)) + (bflo(g2.z) + bflo(g3.z))) + ((bflo(g4.z) + bflo(g5.z)) + (bflo(g6.z) + bflo(g7.z)));
    acc[5] += ((bfhi(g0.z) + bfhi(g1.z)) + (bfhi(g2.z) + bfhi(g3.z))) + ((bfhi(g4.z) + bfhi(g5.z)) + (bfhi(g6.z) + bfhi(g7.z)));
    acc[6] += ((bflo(g0.w) + bflo(g1.w)) + (bflo(g2.w) + bflo(g3.w))) + ((bflo(g4.w) + bflo(g5.w)) + (bflo(g6.w) + bflo(g7.w)));
    acc[7] += ((bfhi(g0.w) + bfhi(g1.w)) + (bfhi(g2.w) + bfhi(g3.w))) + ((bfhi(g4.w) + bfhi(g5.w)) + (bfhi(g6.w) + bfhi(g7.w)));
  }
  uint4 sv = *(const uint4*)(S + (size_t)w * 64);
  float selfv[8] = { bflo(sv.x), bfhi(sv.x), bflo(sv.y), bfhi(sv.y),
                     bflo(sv.z), bfhi(sv.z), bflo(sv.w), bfhi(sv.w) };
  int colOff = slice * 64 + fl * 8;
  float4 b0 = *(const float4*)(bias + colOff);
  float4 b1 = *(const float4*)(bias + colOff + 4);
  float4 r0, r1;
  r0.x = (acc[0] + selfv[0]) * di + b0.x;
  r0.y = (acc[1] + selfv[1]) * di + b0.y;
  r0.z = (acc[2] + selfv[2]) * di + b0.z;
  r0.w = (acc[3] + selfv[3]) * di + b0.w;
  r1.x = (acc[4] + selfv[4]) * di + b1.x;
  r1.y = (acc[5] + selfv[5]) * di + b1.y;
  r1.z = (acc[6] + selfv[6]) * di + b1.z;
  r1.w = (acc[7] + selfv[7]) * di + b1.w;
  *(float4*)(out + (size_t)w * 128 + colOff)     = r0;
  *(float4*)(out + (size_t)w * 128 + colOff + 4) = r1;
}

// ---------------- final layer: aggregation + fused log_softmax (fp32) ----------------

__global__ __launch_bounds__(256) void k_agg32lsm(const float* __restrict__ H2,
                                                  const float* __restrict__ dis,
                                                  const int* __restrict__ rowstart,
                                                  const int* __restrict__ csr_src,
                                                  const float* __restrict__ bias,
                                                  float* __restrict__ out) {
  int wave = (blockIdx.x * 256 + threadIdx.x) >> 6;
  int lane = threadIdx.x & 63;
  int half = lane >> 5;
  int l = lane & 31;
  int hbase = half * 32;
  int w = wave * 2 + half;
  if (w >= NN) return;   // NN even: both halves exit together
  const float* __restrict__ S = H2 + l;
  float di = dis[w];
  int e0 = rowstart[w], e1 = rowstart[w + 1];
  float acc = 0.f;
  for (int e = e0; e < e1; e += 8) {
    int myIdx = csr_src[e + (l & 7)];
    int s0 = __shfl(myIdx, hbase + 0), s1 = __shfl(myIdx, hbase + 1);
    int s2 = __shfl(myIdx, hbase + 2), s3 = __shfl(myIdx, hbase + 3);
    int s4 = __shfl(myIdx, hbase + 4), s5 = __shfl(myIdx, hbase + 5);
    int s6 = __shfl(myIdx, hbase + 6), s7 = __shfl(myIdx, hbase + 7);
    float h0 = S[(size_t)s0 * 32], h1 = S[(size_t)s1 * 32];
    float h2v = S[(size_t)s2 * 32], h3 = S[(size_t)s3 * 32];
    float h4 = S[(size_t)s4 * 32], h5 = S[(size_t)s5 * 32];
    float h6 = S[(size_t)s6 * 32], h7 = S[(size_t)s7 * 32];
    acc += ((h0 + h1) + (h2v + h3)) + ((h4 + h5) + (h6 + h7));
  }
  float v = (acc + S[(size_t)w * 32]) * di + bias[l];
  float m = v;
  #pragma unroll
  for (int off = 16; off >= 1; off >>= 1) m = fmaxf(m, __shfl_xor(m, off));
  float ex = expf(v - m);
  float s = ex;
  #pragma unroll
  for (int off = 16; off >= 1; off >>= 1) s += __shfl_xor(s, off);
  out[(size_t)w * 32 + l] = v - m - logf(s);
}

// ---------------- BatchNorm stats + fused BN/ReLU/residual ----------------

__global__ __launch_bounds__(256) void k_bnstats(const float* __restrict__ O, float* __restrict__ gsum,
                                                 float* __restrict__ gsumsq) {
  int tid = threadIdx.x;
  int f = tid & 127;
  int half = tid >> 7;
  float s = 0.f, sq = 0.f;
  for (int r = blockIdx.x * 2 + half; r < NN; r += gridDim.x * 2) {
    float v = O[(size_t)r * 128 + f];
    s += v; sq += v * v;
  }
  __shared__ float sm[256], sm2[256];
  sm[tid] = s; sm2[tid] = sq;
  __syncthreads();
  if (tid < 128) {
    atomicAdd(&gsum[f], sm[tid] + sm[tid + 128]);
    atomicAdd(&gsumsq[f], sm2[tid] + sm2[tid + 128]);
  }
}

// fused BN (inline mu/istd from raw sums) + ReLU + residual
__global__ __launch_bounds__(256) void k_fuse(const float* __restrict__ O, const float* Xin, float* Xout,
                                              const float* __restrict__ gsum, const float* __restrict__ gsumsq,
                                              const float* __restrict__ g, const float* __restrict__ be) {
  int i = blockIdx.x * 256 + threadIdx.x;
  if (i >= NN * 128 / 4) return;
  int f = (i * 4) & 127;
  float4 ov = ((const float4*)O)[i];
  float4 xv = ((const float4*)Xin)[i];
  float4 r;
  const float inv = 1.f / (float)NN;
  #pragma unroll
  for (int j = 0; j < 4; j++) {
    float m = gsum[f + j] * inv;
    float var = gsumsq[f + j] * inv - m * m;
    float istd = rsqrtf(var + 1e-5f);
    float o = (&ov.x)[j];
    float xx = (&xv.x)[j];
    (&r.x)[j] = fmaxf((o - m) * istd * g[f + j] + be[f + j], 0.f) + xx;
  }
  ((float4*)Xout)[i] = r;
}

// ---------------- launch ----------------

extern "C" void kernel_launch(void* const* d_in, const int* in_sizes, int n_in,
                              void* d_out, int out_size, void* d_ws, size_t ws_size,
                              hipStream_t stream) {
  const float* x   = (const float*)d_in[0];
  const int*   ei  = (const int*)d_in[1];
  const float* W0  = (const float*)d_in[2];
  const float* b0  = (const float*)d_in[3];
  const float* g0  = (const float*)d_in[4];
  const float* be0 = (const float*)d_in[5];
  const float* W1  = (const float*)d_in[6];
  const float* b1  = (const float*)d_in[7];
  const float* g1  = (const float*)d_in[8];
  const float* be1 = (const float*)d_in[9];
  const float* W2  = (const float*)d_in[10];
  const float* b2  = (const float*)d_in[11];
  float* out = (float*)d_out;
  const int* srcI = ei;
  const int* dstI = ei + NE;

  char* p = (char*)d_ws;
  auto take = [&](size_t bytes) { char* r = p; p += (bytes + 255) & ~(size_t)255; return (void*)r; };
  int*   deg8     = (int*)take((size_t)8 * NN * 4);
  int*   cursor   = (int*)take(NN * 4);
  int*   degtot   = (int*)take(NN * 4);
  int*   rowstart = (int*)take((NN + 1) * 4);
  int*   blksum   = (int*)take(64 * 4);
  int*   blkoff   = (int*)take(64 * 4);
  int*   binCnt   = (int*)take(8 * 4);
  float* dis      = (float*)take(NN * 4);
  int*   csr      = (int*)take((size_t)NEP * 4);
  int2*  bin      = (int2*)take((size_t)NBKT * BCAP * 8);
  float* gstat    = (float*)take(512 * 4);   // layer0: [0..255], layer1: [256..511]
  unsigned short* wt16 = (unsigned short*)take((2 * 16384 + 4096) * 2);  // W0^T, W1^T, W2^T bf16
  unsigned short* hs16 = (unsigned short*)take((size_t)NNP * 128 * 2);   // bf16, 2-slice-major
  float* o        = (float*)take((size_t)NN * 128 * 4);
  float* xA       = (float*)take((size_t)NN * 128 * 4);
  float* h2       = (float*)take((size_t)NNP * 32 * 4);

  k_init<<<(NEP + 255) / 256, 256, 0, stream>>>(deg8, gstat, csr, binCnt, W0, W1, W2, wt16);
  k_binA<<<(NE + 1023) / 1024, 1024, 0, stream>>>(srcI, dstI, deg8, binCnt, bin);
  k_scan1<<<NBLK, 1024, 0, stream>>>(deg8, degtot, rowstart, blksum);
  k_scan2<<<1, 64, 0, stream>>>(blksum, blkoff, rowstart);
  k_scan3<<<(NN + 255) / 256, 256, 0, stream>>>(rowstart, blkoff, degtot, cursor, dis, hs16, h2);
  k_fillB<<<512, 256, 0, stream>>>(bin, binCnt, cursor, csr);

  const int aggGrid = ((NN + 31) / 32) * 2;  // 32 nodes/block x 2 slices

  // ---- layer 0 ----
  k_gemm128<<<(NN + 63) / 64, 256, 0, stream>>>(x, wt16, dis, hs16, NN);
  k_agg128<<<aggGrid, 256, 0, stream>>>(hs16, dis, rowstart, csr, b0, o);
  k_bnstats<<<1024, 256, 0, stream>>>(o, gstat, gstat + 128);
  k_fuse<<<(NN * 128 / 4 + 255) / 256, 256, 0, stream>>>(o, x, xA, gstat, gstat + 128, g0, be0);

  // ---- layer 1 ----
  k_gemm128<<<(NN + 63) / 64, 256, 0, stream>>>(xA, wt16 + 16384, dis, hs16, NN);
  k_agg128<<<aggGrid, 256, 0, stream>>>(hs16, dis, rowstart, csr, b1, o);
  k_bnstats<<<1024, 256, 0, stream>>>(o, gstat + 256, gstat + 384);
  k_fuse<<<(NN * 128 / 4 + 255) / 256, 256, 0, stream>>>(o, xA, xA, gstat + 256, gstat + 384, g1, be1);

  // ---- final conv (MFMA) + fused aggregation/log_softmax ----
  k_gemm32m<<<(NN + 63) / 64, 256, 0, stream>>>(xA, wt16 + 32768, dis, h2, NN);
  k_agg32lsm<<<(NN + 7) / 8, 256, 0, stream>>>(h2, dis, rowstart, csr, b2, out);
}